// Round 10
// baseline (3479.530 us; speedup 1.0000x reference)
//
#include <hip/hip_runtime.h>
#include <stdint.h>
#include <stdio.h>

#define NOUT 512
#define NSEG 1024

typedef unsigned short u16;
typedef __attribute__((ext_vector_type(4))) float f32x4;
typedef __attribute__((ext_vector_type(8))) short s16x8;
typedef __attribute__((ext_vector_type(4))) unsigned short u16x4;

__device__ __forceinline__ u16 f2b(float f) {
  union { float f; uint32_t u; } v; v.f = f;
  uint32_t r = v.u + 0x7FFFu + ((v.u >> 16) & 1u);
  return (u16)(r >> 16);
}
__device__ __forceinline__ float b2f(u16 b) {
  union { uint32_t u; float f; } v; v.u = ((uint32_t)b) << 16;
  return v.f;
}

typedef __attribute__((address_space(1))) const void GAS;
typedef __attribute__((address_space(3))) void LAS;
__device__ __forceinline__ void llds16(const void* g, void* l) {
  __builtin_amdgcn_global_load_lds((GAS*)g, (LAS*)l, 16, 0, 0);
}

// w: [K][512] f32 -> out: [512][K] bf16 (B^T), coalesced both sides via LDS tile
__global__ void k_wtcastT(const float* __restrict__ w, u16* __restrict__ out, int K) {
  __shared__ float tile[32][33];
  int k0 = blockIdx.x * 32, c0 = blockIdx.y * 32;
  int t = threadIdx.x;  // 256
  int rr = t >> 5, cc = t & 31;
#pragma unroll
  for (int p = 0; p < 4; ++p)
    tile[p * 8 + rr][cc] = w[(long)(k0 + p * 8 + rr) * NOUT + c0 + cc];
  __syncthreads();
#pragma unroll
  for (int p = 0; p < 4; ++p)
    out[(long)(c0 + p * 8 + rr) * K + k0 + cc] = f2b(tile[cc][p * 8 + rr]);
}

// ---------------- segment sort ----------------
__global__ void k_hist(const int* __restrict__ ele, int* __restrict__ cnt, int N) {
  int i = blockIdx.x * blockDim.x + threadIdx.x;
  int stride = gridDim.x * blockDim.x;
  for (; i < N; i += stride) atomicAdd(&cnt[ele[i]], 1);
}

__global__ void k_scan(const int* __restrict__ cnt, int* __restrict__ off) {
  __shared__ int tmp[NSEG];
  int t = threadIdx.x;
  tmp[t] = cnt[t];
  __syncthreads();
  for (int o = 1; o < NSEG; o <<= 1) {
    int add = (t >= o) ? tmp[t - o] : 0;
    __syncthreads();
    tmp[t] += add;
    __syncthreads();
  }
  off[t] = tmp[t] - cnt[t];
}

__global__ void k_scatter(const int* __restrict__ ele, const int* __restrict__ off,
                          int* __restrict__ fill, int* __restrict__ rows, int N) {
  int i = blockIdx.x * blockDim.x + threadIdx.x;
  int stride = gridDim.x * blockDim.x;
  for (; i < N; i += stride) {
    int e = ele[i];
    int p = atomicAdd(&fill[e], 1);
    rows[off[e] + p] = i;
  }
}

// ---------------- BN finalize ----------------
__global__ void k_finalize(const float* __restrict__ sum, const float* __restrict__ sumsq,
                           const float* __restrict__ g, const float* __restrict__ be,
                           float* __restrict__ A, float* __restrict__ C, int M) {
  int c = threadIdx.x;  // 512
  float m = sum[c] / (float)M;
  float v = sumsq[c] / (float)M - m * m;
  float a = g[c] * rsqrtf(v + 1e-5f);
  A[c] = a;
  C[c] = be[c] - a * m;
}

// ---------------- fused BN-apply + ReLU + segment mean (full row per block) ----------------
__global__ void k_bnseg(const u16* __restrict__ hp, u16* __restrict__ h, u16* __restrict__ mean,
                        const float* __restrict__ A, const float* __restrict__ C,
                        const int* __restrict__ off, const int* __restrict__ cnt,
                        const int* __restrict__ rows) {
  int s = blockIdx.x;
  int c0 = 2 * threadIdx.x;  // 256 threads -> cols c0, c0+1
  int n = cnt[s], o = off[s];
  float a0 = A[c0], a1 = A[c0 + 1], cc0 = C[c0], cc1 = C[c0 + 1];
  float s0 = 0.f, s1 = 0.f;
#pragma unroll 2
  for (int j = 0; j < n; ++j) {
    int r = rows[o + j];
    uint32_t v = *reinterpret_cast<const uint32_t*>(&hp[(long)r * NOUT + c0]);
    float h0 = fmaxf(a0 * b2f((u16)(v & 0xffff)) + cc0, 0.f);
    float h1 = fmaxf(a1 * b2f((u16)(v >> 16)) + cc1, 0.f);
    s0 += h0; s1 += h1;
    *reinterpret_cast<uint32_t*>(&h[(long)r * NOUT + c0]) =
        ((uint32_t)f2b(h1) << 16) | (uint32_t)f2b(h0);
  }
  float inv = 1.f / fmaxf((float)n, 1.f);
  *reinterpret_cast<uint32_t*>(&mean[(long)s * NOUT + c0]) =
      ((uint32_t)f2b(s1 * inv) << 16) | (uint32_t)f2b(s0 * inv);
}

__global__ void k_final(const u16* __restrict__ hp, float* __restrict__ out,
                        const float* __restrict__ A, const float* __restrict__ C, long n4) {
  long i = blockIdx.x * (long)blockDim.x + threadIdx.x;
  long stride = (long)gridDim.x * blockDim.x;
  for (; i < n4; i += stride) {
    u16x4 v = reinterpret_cast<const u16x4*>(hp)[i];
    int c0 = (int)((i * 4) & (NOUT - 1));
    float4 a = *reinterpret_cast<const float4*>(&A[c0]);
    float4 c = *reinterpret_cast<const float4*>(&C[c0]);
    float4 o;
    o.x = fmaxf(a.x * b2f(v.x) + c.x, 0.f);
    o.y = fmaxf(a.y * b2f(v.y) + c.y, 0.f);
    o.z = fmaxf(a.z * b2f(v.z) + c.z, 0.f);
    o.w = fmaxf(a.w * b2f(v.w) + c.w, 0.f);
    reinterpret_cast<float4*>(out)[i] = o;
  }
}

// ---------------- GEMM: C[M,512] = A[M,K] @ W[K,512] ----------------
// R6/R9 2-phase skeleton (proven local opt): dual 16KB LDS buffers; per K-tile:
//   ISSUE(t+1: A f32 reg-loads or A gload_lds; B gload_lds) -> ds_read(cur) -> MFMA
//   -> COMMIT(t+1: cvt+ds_write for f32 regions) -> __syncthreads.
// f32-A fusion (T14 issue-early/write-late): FA0/FA1 template flags mark A-regions
// sourced as f32 (x, dist) -- converted in-register, killing the standalone cast
// kernels. Loads fly under the MFMA cluster; cvt's vmcnt-wait lands after MFMA.
// MFMA operands SWAPPED (mfma(bf, af)) -> output transposed: lane holds row=l15,
// cols=kg*4+j (4 consecutive) -> 8B/16B C-stores, float4 tab gather.
// LDS [128][32] u16, conflict-free chunk swizzle ^=(row>>1)&3 (measured 0 conflicts):
// bf16 path = inverse-permuted gload_lds source; f32 path = swizzled ds_write addr.
// Biases dropped everywhere (cancel in training-mode BN).
template <bool FA0, bool FA1>
__global__ __launch_bounds__(256, 4) void k_gemm(
    const u16* p0, const u16* p1, const float* f0, const float* f1,
    int e0, int w0, int w1, int g0, int g1,
    const int* __restrict__ ele,
    const u16* __restrict__ wbt, int ldb, int e0b, int bskip,
    const float* __restrict__ tab, int addtab,
    u16* __restrict__ outp, float* __restrict__ outf, int wf32,
    float* __restrict__ csum, float* __restrict__ csq, int dostats,
    int M, int K) {
  __shared__ __align__(16) u16 As[2 * 4096];
  __shared__ __align__(16) u16 Bs[2 * 4096];

  int nwg = gridDim.x;
  int orig = blockIdx.x;
  // bijective XCD swizzle (m204)
  int q = nwg >> 3, r8 = nwg & 7;
  int xcd = orig & 7, loc = orig >> 3;
  int bid = (xcd < r8 ? xcd * (q + 1) : r8 * (q + 1) + (xcd - r8) * q) + loc;
  int mt = bid >> 2, ct = bid & 3;  // 4 col-tiles of same mt adjacent -> L2 A reuse
  int brow = mt * 128, bcol = ct * 128;

  int tid = (int)threadIdx.x;
  int lane = tid & 63;
  int wid = tid >> 6;
  int wr = wid >> 1, wc = wid & 1;  // 2x2 waves, 64x64 each
  int l15 = lane & 15, kg = lane >> 4;

  // ---- bf16-A + B staging mapping (gload_lds; inverse-swizzled source) ----
  int srow = tid >> 2;                             // 0..63
  int soct = ((tid & 3) ^ ((srow >> 1) & 3)) * 8;  // u16 source col-octet

  const u16 *a00 = nullptr, *a01 = nullptr, *a10 = nullptr, *a11 = nullptr;
  if constexpr (!FA0 || !FA1) {
    int gr0 = brow + srow, gr1 = gr0 + 64;
    int gr0c = gr0 < M ? gr0 : M - 1;
    int gr1c = gr1 < M ? gr1 : M - 1;
    int el0 = (g0 | g1) ? ele[gr0c] : 0, el1 = (g0 | g1) ? ele[gr1c] : 0;
    a00 = p0 + (long)(g0 ? el0 : gr0c) * w0 + soct;
    a01 = p1 + (long)(g1 ? el0 : gr0c) * w1 + soct;
    a10 = p0 + (long)(g0 ? el1 : gr1c) * w0 + soct;
    a11 = p1 + (long)(g1 ? el1 : gr1c) * w1 + soct;
  }
  const u16* b0p = wbt + (long)(bcol + srow) * ldb + soct;        // cols < 512
  const u16* b1p = wbt + (long)(bcol + srow + 64) * ldb + soct;

  // ---- f32-A staging mapping (reg-load + cvt + swizzled ds_write) ----
  int fs = tid & 7;   // 8B-slot within 64B bf16 row (== float4 slot in f32 source)
  int fr = tid >> 3;  // 0..31 -> rows fr + {0,32,64,96}
  long fro0[4], fro1[4];
  int fdst[4];
  if constexpr (FA0 || FA1) {
#pragma unroll
    for (int i = 0; i < 4; ++i) {
      int rl = fr + 32 * i;
      int gr = brow + rl;
      if (gr >= M) gr = M - 1;
      fro0[i] = (long)gr * w0;
      fro1[i] = (long)gr * w1;
      fdst[i] = rl * 32 + (fs ^ ((((rl >> 1) & 3)) << 1)) * 4;  // u16 units
    }
  }
  float4 la[4];

  // swizzled fragment-read offsets (u16 index within one 4096-u16 buffer)
  int xoct = (kg ^ ((l15 >> 1) & 3)) * 8;
  int aro = (wr * 64 + l15) * 32 + xoct;
  int bro = (wc * 64 + l15) * 32 + xoct;

  f32x4 acc[4][4];
#pragma unroll
  for (int m = 0; m < 4; ++m)
#pragma unroll
    for (int n = 0; n < 4; ++n)
#pragma unroll
      for (int j = 0; j < 4; ++j) acc[m][n][j] = 0.f;

  int KT = K >> 5;
  int dst = wid * 512;  // per-wave linear 1KB dest region (u16)

  auto issueA = [&](int tt, int buf) {
    int k0 = tt << 5;
    if (k0 < e0) {
      if constexpr (FA0) {
#pragma unroll
        for (int i = 0; i < 4; ++i)
          la[i] = *reinterpret_cast<const float4*>(f0 + fro0[i] + k0 + fs * 4);
      } else {
        int ab = buf * 4096 + dst;
        llds16(a00 + k0, &As[ab]);
        llds16(a10 + k0, &As[ab + 2048]);
      }
    } else {
      int ko = k0 - e0;
      if constexpr (FA1) {
#pragma unroll
        for (int i = 0; i < 4; ++i)
          la[i] = *reinterpret_cast<const float4*>(f1 + fro1[i] + ko + fs * 4);
      } else {
        int ab = buf * 4096 + dst;
        llds16(a01 + ko, &As[ab]);
        llds16(a11 + ko, &As[ab + 2048]);
      }
    }
  };
  auto commitA = [&](int tt, int buf) {
    int k0 = tt << 5;
    bool isf = (k0 < e0) ? FA0 : FA1;
    if (isf) {
      int ab = buf * 4096;
#pragma unroll
      for (int i = 0; i < 4; ++i) {
        u16x4 pk;
        pk.x = f2b(la[i].x); pk.y = f2b(la[i].y);
        pk.z = f2b(la[i].z); pk.w = f2b(la[i].w);
        *reinterpret_cast<u16x4*>(&As[ab + fdst[i]]) = pk;
      }
    }
  };
  auto issueB = [&](int tt, int buf) {
    int k0 = tt << 5;
    int bo = k0 + (k0 >= e0b ? bskip : 0);
    int ab = buf * 4096 + dst;
    llds16(b0p + bo, &Bs[ab]);
    llds16(b1p + bo, &Bs[ab + 2048]);
  };

  issueA(0, 0);
  issueB(0, 0);
  commitA(0, 0);
  __syncthreads();

  for (int t = 0; t < KT; ++t) {
    int cur = t & 1;
    if (t + 1 < KT) {
      issueA(t + 1, cur ^ 1);
      issueB(t + 1, cur ^ 1);
    }
    __builtin_amdgcn_sched_barrier(0);
    const u16* Ab = &As[cur * 4096];
    const u16* Bb = &Bs[cur * 4096];
    s16x8 af[4], bf[4];
#pragma unroll
    for (int m = 0; m < 4; ++m)
      af[m] = *reinterpret_cast<const s16x8*>(&Ab[m * 512 + aro]);
#pragma unroll
    for (int n = 0; n < 4; ++n)
      bf[n] = *reinterpret_cast<const s16x8*>(&Bb[n * 512 + bro]);
#pragma unroll
    for (int m = 0; m < 4; ++m)
#pragma unroll
      for (int n = 0; n < 4; ++n)  // swapped operands -> transposed C layout
        acc[m][n] = __builtin_amdgcn_mfma_f32_16x16x32_bf16(bf[n], af[m], acc[m][n], 0, 0, 0);
    __builtin_amdgcn_sched_barrier(0);
    if (t + 1 < KT) commitA(t + 1, cur ^ 1);
    __syncthreads();
  }

  // epilogue (transposed layout): lane -> row = base + l15, cols = colbase + kg*4 + j
  f32x4 sums4[4], sqs4[4];
#pragma unroll
  for (int n = 0; n < 4; ++n)
#pragma unroll
    for (int j = 0; j < 4; ++j) { sums4[n][j] = 0.f; sqs4[n][j] = 0.f; }
#pragma unroll
  for (int m = 0; m < 4; ++m) {
    int row = brow + wr * 64 + m * 16 + l15;
    bool ok = row < M;
    long rb = (long)(ok ? row : 0) * NOUT;
    long tb = (addtab && ok) ? (long)ele[row] * NOUT : 0;
#pragma unroll
    for (int n = 0; n < 4; ++n) {
      int col0 = bcol + wc * 64 + n * 16 + kg * 4;
      f32x4 v = acc[m][n];
      if (addtab && ok) {
        float4 tv = *reinterpret_cast<const float4*>(&tab[tb + col0]);
        v[0] += tv.x; v[1] += tv.y; v[2] += tv.z; v[3] += tv.w;
      }
      if (ok) {
        if (wf32) {
          *reinterpret_cast<f32x4*>(&outf[rb + col0]) = v;
        } else {
          u16x4 pk;
          pk.x = f2b(v[0]); pk.y = f2b(v[1]); pk.z = f2b(v[2]); pk.w = f2b(v[3]);
          *reinterpret_cast<u16x4*>(&outp[rb + col0]) = pk;
        }
#pragma unroll
        for (int j = 0; j < 4; ++j) { sums4[n][j] += v[j]; sqs4[n][j] += v[j] * v[j]; }
      }
    }
  }
  if (dostats) {
#pragma unroll
    for (int n = 0; n < 4; ++n)
#pragma unroll
      for (int d = 1; d < 16; d <<= 1)
#pragma unroll
        for (int j = 0; j < 4; ++j) {
          sums4[n][j] += __shfl_xor(sums4[n][j], d);
          sqs4[n][j] += __shfl_xor(sqs4[n][j], d);
        }
    if (l15 == 0) {
#pragma unroll
      for (int n = 0; n < 4; ++n) {
        int col0 = bcol + wc * 64 + n * 16 + kg * 4;
#pragma unroll
        for (int j = 0; j < 4; ++j) {
          atomicAdd(&csum[col0 + j], sums4[n][j]);
          atomicAdd(&csq[col0 + j], sqs4[n][j]);
        }
      }
    }
  }
}

// ---------------- host ----------------
extern "C" void kernel_launch(void* const* d_in, const int* in_sizes, int n_in,
                              void* d_out, int out_size, void* d_ws, size_t ws_size,
                              hipStream_t stream) {
  const float* x    = (const float*)d_in[0];
  const float* dist = (const float*)d_in[1];
  const int* ele    = (const int*)d_in[3];
  const float* l1w  = (const float*)d_in[4];
  const float* l1g  = (const float*)d_in[6];
  const float* l1be = (const float*)d_in[7];
  const float* l2w  = (const float*)d_in[8];
  const float* l2g  = (const float*)d_in[10];
  const float* l2be = (const float*)d_in[11];
  const float* fw   = (const float*)d_in[12];
  const float* fg   = (const float*)d_in[14];
  const float* fbe  = (const float*)d_in[15];

  int N = in_sizes[0] / 1024;  // 100000
  float* out = (float*)d_out;

  int MT = (N + 127) / 128;    // 782

  char* w = (char*)d_ws;
  auto alloc = [&](size_t bytes) {
    char* p = w;
    w += (bytes + 255) & ~(size_t)255;
    return p;
  };
  u16* hp      = (u16*)alloc((size_t)N * NOUT * 2);
  u16* h       = (u16*)alloc((size_t)N * NOUT * 2);
  u16* mean    = (u16*)alloc((size_t)NSEG * NOUT * 2);
  u16* w1bt    = (u16*)alloc((size_t)NOUT * 1280 * 2);
  u16* w2bt    = (u16*)alloc((size_t)NOUT * 1280 * 2);
  u16* fbt     = (u16*)alloc((size_t)NOUT * 1024 * 2);
  float* mc2   = (float*)alloc((size_t)NSEG * NOUT * 4);
  float* mc3   = (float*)alloc((size_t)NSEG * NOUT * 4);
  float* colsum = (float*)alloc(NOUT * 4 * 2);
  float* colsumsq = colsum + NOUT;
  float* bnA   = (float*)alloc(NOUT * 4);
  float* bnC   = (float*)alloc(NOUT * 4);
  int* seg_cnt = (int*)alloc(NSEG * 4);
  int* seg_off = (int*)alloc(NSEG * 4);
  int* seg_fill = (int*)alloc(NSEG * 4);
  int* rows    = (int*)alloc((size_t)N * 4);

  size_t need = (size_t)(w - (char*)d_ws);
  if (need > ws_size) {
    fprintf(stderr, "kernel_launch: ws too small: need %zu have %zu\n", need, ws_size);
    return;
  }

  long n4h = (long)N * NOUT / 4;
  int gemmGrid = MT * 4;          // 3128
  int mcGrid = (NSEG / 128) * 4;  // 32

  // weight transpose+cast
  dim3 wt1(1280 / 32, 16), wt3(1024 / 32, 16);
  k_wtcastT<<<wt1, 256, 0, stream>>>(l1w, w1bt, 1280);
  k_wtcastT<<<wt1, 256, 0, stream>>>(l2w, w2bt, 1280);
  k_wtcastT<<<wt3, 256, 0, stream>>>(fw, fbt, 1024);

  // segment sort
  hipMemsetAsync(seg_cnt, 0, NSEG * 4, stream);
  hipMemsetAsync(seg_fill, 0, NSEG * 4, stream);
  k_hist<<<512, 256, 0, stream>>>(ele, seg_cnt, N);
  k_scan<<<1, NSEG, 0, stream>>>(seg_cnt, seg_off);
  k_scatter<<<512, 256, 0, stream>>>(ele, seg_off, seg_fill, rows, N);

  // ---- layer 1: A = [x(1024,f32) | dist(256,f32)], K=1280, casts fused ----
  hipMemsetAsync(colsum, 0, NOUT * 4 * 2, stream);
  k_gemm<true, true><<<gemmGrid, 256, 0, stream>>>(
      hp, hp, x, dist, 1024, 1024, 256, 0, 0, ele,
      w1bt, 1280, 1280, 0, mc2, 0,
      hp, mc2, 0, colsum, colsumsq, 1, N, 1280);
  k_finalize<<<1, NOUT, 0, stream>>>(colsum, colsumsq, l1g, l1be, bnA, bnC, N);
  k_bnseg<<<NSEG, 256, 0, stream>>>(hp, h, mean, bnA, bnC, seg_off, seg_cnt, rows);

  // ---- layer 2: mc2 = mean @ W2[512:1024); A = [h(512,bf16) | dist(256,f32)], K=768 ----
  k_gemm<false, false><<<mcGrid, 256, 0, stream>>>(
      mean, mean, x, dist, 512, 512, 512, 0, 0, ele,
      w2bt + 512, 1280, 512, 0, mc2, 0,
      hp, mc2, 1, colsum, colsumsq, 0, NSEG, 512);
  hipMemsetAsync(colsum, 0, NOUT * 4 * 2, stream);
  k_gemm<false, true><<<gemmGrid, 256, 0, stream>>>(
      h, hp, x, dist, 512, 512, 256, 0, 0, ele,
      w2bt, 1280, 512, 512, mc2, 1,
      hp, mc2, 0, colsum, colsumsq, 1, N, 768);
  k_finalize<<<1, NOUT, 0, stream>>>(colsum, colsumsq, l2g, l2be, bnA, bnC, N);
  k_bnseg<<<NSEG, 256, 0, stream>>>(hp, h, mean, bnA, bnC, seg_off, seg_cnt, rows);

  // ---- final layer: mc3 = mean @ F[512:1024); A = h(bf16), K=512 ----
  k_gemm<false, false><<<mcGrid, 256, 0, stream>>>(
      mean, mean, x, dist, 512, 512, 512, 0, 0, ele,
      fbt + 512, 1024, 512, 0, mc3, 0,
      hp, mc3, 1, colsum, colsumsq, 0, NSEG, 512);
  hipMemsetAsync(colsum, 0, NOUT * 4 * 2, stream);
  k_gemm<false, false><<<gemmGrid, 256, 0, stream>>>(
      h, h, x, dist, 512, 512, 512, 0, 0, ele,
      fbt, 1024, 512, 0, mc3, 1,
      hp, mc3, 0, colsum, colsumsq, 1, N, 512);
  k_finalize<<<1, NOUT, 0, stream>>>(colsum, colsumsq, fg, fbe, bnA, bnC, N);
  k_final<<<4096, 256, 0, stream>>>(hp, out, bnA, bnC, n4h);
}

// Round 11
// 2684.267 us; speedup vs baseline: 1.2963x; 1.2963x over previous
//
#include <hip/hip_runtime.h>
#include <stdint.h>
#include <stdio.h>

#define NOUT 512
#define NSEG 1024

typedef unsigned short u16;
typedef __attribute__((ext_vector_type(4))) float f32x4;
typedef __attribute__((ext_vector_type(8))) short s16x8;
typedef __attribute__((ext_vector_type(4))) unsigned short u16x4;

__device__ __forceinline__ u16 f2b(float f) {
  union { float f; uint32_t u; } v; v.f = f;
  uint32_t r = v.u + 0x7FFFu + ((v.u >> 16) & 1u);
  return (u16)(r >> 16);
}
__device__ __forceinline__ float b2f(u16 b) {
  union { uint32_t u; float f; } v; v.u = ((uint32_t)b) << 16;
  return v.f;
}

typedef __attribute__((address_space(1))) const void GAS;
typedef __attribute__((address_space(3))) void LAS;
__device__ __forceinline__ void llds16(const void* g, void* l) {
  __builtin_amdgcn_global_load_lds((GAS*)g, (LAS*)l, 16, 0, 0);
}

// ---------------- cast kernels ----------------
__global__ void k_cast(const float* __restrict__ src, u16* __restrict__ dst, long n4) {
  long i = blockIdx.x * (long)blockDim.x + threadIdx.x;
  long stride = (long)gridDim.x * blockDim.x;
  for (; i < n4; i += stride) {
    float4 v = reinterpret_cast<const float4*>(src)[i];
    u16x4 o;
    o.x = f2b(v.x); o.y = f2b(v.y); o.z = f2b(v.z); o.w = f2b(v.w);
    reinterpret_cast<u16x4*>(dst)[i] = o;
  }
}

// w: [K][512] f32 -> out: [512][K] bf16 (B^T), coalesced both sides via LDS tile
__global__ void k_wtcastT(const float* __restrict__ w, u16* __restrict__ out, int K) {
  __shared__ float tile[32][33];
  int k0 = blockIdx.x * 32, c0 = blockIdx.y * 32;
  int t = threadIdx.x;  // 256
  int rr = t >> 5, cc = t & 31;
#pragma unroll
  for (int p = 0; p < 4; ++p)
    tile[p * 8 + rr][cc] = w[(long)(k0 + p * 8 + rr) * NOUT + c0 + cc];
  __syncthreads();
#pragma unroll
  for (int p = 0; p < 4; ++p)
    out[(long)(c0 + p * 8 + rr) * K + k0 + cc] = f2b(tile[cc][p * 8 + rr]);
}

// ---------------- segment sort ----------------
__global__ void k_hist(const int* __restrict__ ele, int* __restrict__ cnt, int N) {
  int i = blockIdx.x * blockDim.x + threadIdx.x;
  int stride = gridDim.x * blockDim.x;
  for (; i < N; i += stride) atomicAdd(&cnt[ele[i]], 1);
}

__global__ void k_scan(const int* __restrict__ cnt, int* __restrict__ off) {
  __shared__ int tmp[NSEG];
  int t = threadIdx.x;
  tmp[t] = cnt[t];
  __syncthreads();
  for (int o = 1; o < NSEG; o <<= 1) {
    int add = (t >= o) ? tmp[t - o] : 0;
    __syncthreads();
    tmp[t] += add;
    __syncthreads();
  }
  off[t] = tmp[t] - cnt[t];
}

__global__ void k_scatter(const int* __restrict__ ele, const int* __restrict__ off,
                          int* __restrict__ fill, int* __restrict__ rows, int N) {
  int i = blockIdx.x * blockDim.x + threadIdx.x;
  int stride = gridDim.x * blockDim.x;
  for (; i < N; i += stride) {
    int e = ele[i];
    int p = atomicAdd(&fill[e], 1);
    rows[off[e] + p] = i;
  }
}

// ---------------- BN finalize (also self-clears the accumulators for the next layer) ----------------
__global__ void k_finalize(float* __restrict__ sum, float* __restrict__ sumsq,
                           const float* __restrict__ g, const float* __restrict__ be,
                           float* __restrict__ A, float* __restrict__ C, int M) {
  int c = threadIdx.x;  // 512
  float m = sum[c] / (float)M;
  float v = sumsq[c] / (float)M - m * m;
  float a = g[c] * rsqrtf(v + 1e-5f);
  A[c] = a;
  C[c] = be[c] - a * m;
  sum[c] = 0.f;
  sumsq[c] = 0.f;
}

// ---------------- fused BN-apply + ReLU + segment mean (full row per block) ----------------
__global__ void k_bnseg(const u16* __restrict__ hp, u16* __restrict__ h, u16* __restrict__ mean,
                        const float* __restrict__ A, const float* __restrict__ C,
                        const int* __restrict__ off, const int* __restrict__ cnt,
                        const int* __restrict__ rows) {
  int s = blockIdx.x;
  int c0 = 2 * threadIdx.x;  // 256 threads -> cols c0, c0+1
  int n = cnt[s], o = off[s];
  float a0 = A[c0], a1 = A[c0 + 1], cc0 = C[c0], cc1 = C[c0 + 1];
  float s0 = 0.f, s1 = 0.f;
#pragma unroll 2
  for (int j = 0; j < n; ++j) {
    int r = rows[o + j];
    uint32_t v = *reinterpret_cast<const uint32_t*>(&hp[(long)r * NOUT + c0]);
    float h0 = fmaxf(a0 * b2f((u16)(v & 0xffff)) + cc0, 0.f);
    float h1 = fmaxf(a1 * b2f((u16)(v >> 16)) + cc1, 0.f);
    s0 += h0; s1 += h1;
    *reinterpret_cast<uint32_t*>(&h[(long)r * NOUT + c0]) =
        ((uint32_t)f2b(h1) << 16) | (uint32_t)f2b(h0);
  }
  float inv = 1.f / fmaxf((float)n, 1.f);
  *reinterpret_cast<uint32_t*>(&mean[(long)s * NOUT + c0]) =
      ((uint32_t)f2b(s1 * inv) << 16) | (uint32_t)f2b(s0 * inv);
}

__global__ void k_final(const u16* __restrict__ hp, float* __restrict__ out,
                        const float* __restrict__ A, const float* __restrict__ C, long n4) {
  long i = blockIdx.x * (long)blockDim.x + threadIdx.x;
  long stride = (long)gridDim.x * blockDim.x;
  for (; i < n4; i += stride) {
    u16x4 v = reinterpret_cast<const u16x4*>(hp)[i];
    int c0 = (int)((i * 4) & (NOUT - 1));
    float4 a = *reinterpret_cast<const float4*>(&A[c0]);
    float4 c = *reinterpret_cast<const float4*>(&C[c0]);
    float4 o;
    o.x = fmaxf(a.x * b2f(v.x) + c.x, 0.f);
    o.y = fmaxf(a.y * b2f(v.y) + c.y, 0.f);
    o.z = fmaxf(a.z * b2f(v.z) + c.z, 0.f);
    o.w = fmaxf(a.w * b2f(v.w) + c.w, 0.f);
    reinterpret_cast<float4*>(out)[i] = o;
  }
}

// ---------------- GEMM: C[M,512] = A[M,K] @ W[K,512] ----------------
// R9's proven 2-phase loop (dual 16KB LDS buffers; STAGE(t+1) -> ds_read(cur) ->
// MFMA -> __syncthreads) + R10's verified SWAPPED-OPERAND epilogue:
// mfma(bf, af) -> lane holds row=l15, cols=kg*4+j (4 consecutive) -> 8B/16B
// C-stores, float4 tab gather, shfl_xor(1,2,4,8) stats reduce.
// Tile 128x128, BK=32, 4 waves 2x2 (64x64 each), launch_bounds(256,4).
// LDS [128][32] u16; conflict-free swizzle: 16B-chunk ^= (row>>1)&3 (measured 0
// conflicts), inverse-permuted GLOBAL source (m173) + XOR on ds_read (rule #21).
// A: 2 regions (k<e0 -> p0 gather?g0 else p1 gather?g1). B: wbt [512][ldb] (=W^T),
// k += bskip when k>=e0b. Biases dropped (cancel in training-mode BN).
__global__ __launch_bounds__(256, 4) void k_gemm(
    const u16* p0, const u16* p1, int e0, int w0, int w1, int g0, int g1,
    const int* __restrict__ ele,
    const u16* __restrict__ wbt, int ldb, int e0b, int bskip,
    const float* __restrict__ tab, int addtab,
    u16* __restrict__ outp, float* __restrict__ outf, int wf32,
    float* __restrict__ csum, float* __restrict__ csq, int dostats,
    int M, int K) {
  __shared__ __align__(16) u16 As[2 * 4096];
  __shared__ __align__(16) u16 Bs[2 * 4096];

  int nwg = gridDim.x;
  int orig = blockIdx.x;
  // bijective XCD swizzle (m204)
  int q = nwg >> 3, r8 = nwg & 7;
  int xcd = orig & 7, loc = orig >> 3;
  int bid = (xcd < r8 ? xcd * (q + 1) : r8 * (q + 1) + (xcd - r8) * q) + loc;
  int mt = bid >> 2, ct = bid & 3;  // 4 col-tiles of same mt adjacent -> L2 A reuse
  int brow = mt * 128, bcol = ct * 128;

  int tid = (int)threadIdx.x;
  int lane = tid & 63;
  int wid = tid >> 6;
  int wr = wid >> 1, wc = wid & 1;  // 2x2 waves, 64x64 each
  int l15 = lane & 15, kg = lane >> 4;

  // staging: thread t -> row srow(+64), chunk tid&3; source chunk inverse-swizzled
  int srow = tid >> 2;                             // 0..63
  int soct = ((tid & 3) ^ ((srow >> 1) & 3)) * 8;  // u16 source col-octet

  int gr0 = brow + srow, gr1 = gr0 + 64;
  int gr0c = gr0 < M ? gr0 : M - 1;
  int gr1c = gr1 < M ? gr1 : M - 1;
  int el0 = ele[gr0c], el1 = ele[gr1c];

  const u16* a00 = p0 + (long)(g0 ? el0 : gr0c) * w0 + soct;
  const u16* a01 = p1 + (long)(g1 ? el0 : gr0c) * w1 + soct - e0;
  const u16* a10 = p0 + (long)(g0 ? el1 : gr1c) * w0 + soct;
  const u16* a11 = p1 + (long)(g1 ? el1 : gr1c) * w1 + soct - e0;

  const u16* b0p = wbt + (long)(bcol + srow) * ldb + soct;        // cols < 512
  const u16* b1p = wbt + (long)(bcol + srow + 64) * ldb + soct;

  // swizzled fragment-read offsets (u16 index within one 4096-u16 buffer)
  int xoct = (kg ^ ((l15 >> 1) & 3)) * 8;
  int aro = (wr * 64 + l15) * 32 + xoct;
  int bro = (wc * 64 + l15) * 32 + xoct;

  f32x4 acc[4][4];
#pragma unroll
  for (int m = 0; m < 4; ++m)
#pragma unroll
    for (int n = 0; n < 4; ++n)
#pragma unroll
      for (int j = 0; j < 4; ++j) acc[m][n][j] = 0.f;

  int KT = K >> 5;
  int dst = wid * 512;  // u16: per-wave linear 1KB dest region

  auto stage = [&](int tt, int buf) {
    int k0 = tt << 5;
    const u16* sa0 = k0 < e0 ? a00 : a01;
    const u16* sa1 = k0 < e0 ? a10 : a11;
    int bo = k0 + (k0 >= e0b ? bskip : 0);
    int ab = buf * 4096 + dst;
    llds16(sa0 + k0, &As[ab]);
    llds16(sa1 + k0, &As[ab + 2048]);
    llds16(b0p + bo, &Bs[ab]);
    llds16(b1p + bo, &Bs[ab + 2048]);
  };

  stage(0, 0);
  __syncthreads();

  for (int t = 0; t < KT; ++t) {
    int cur = t & 1;
    if (t + 1 < KT) stage(t + 1, cur ^ 1);
    __builtin_amdgcn_sched_barrier(0);
    const u16* Ab = &As[cur * 4096];
    const u16* Bb = &Bs[cur * 4096];
    s16x8 af[4], bf[4];
#pragma unroll
    for (int m = 0; m < 4; ++m)
      af[m] = *reinterpret_cast<const s16x8*>(&Ab[m * 512 + aro]);
#pragma unroll
    for (int n = 0; n < 4; ++n)
      bf[n] = *reinterpret_cast<const s16x8*>(&Bb[n * 512 + bro]);
#pragma unroll
    for (int m = 0; m < 4; ++m)
#pragma unroll
      for (int n = 0; n < 4; ++n)  // swapped operands -> transposed C layout
        acc[m][n] = __builtin_amdgcn_mfma_f32_16x16x32_bf16(bf[n], af[m], acc[m][n], 0, 0, 0);
    __syncthreads();  // drain after MFMA: next-tile loads had the full phase to land
  }

  // epilogue (transposed layout, R10-verified): row = base + l15, cols = colbase + kg*4 + j
  f32x4 sums4[4], sqs4[4];
#pragma unroll
  for (int n = 0; n < 4; ++n)
#pragma unroll
    for (int j = 0; j < 4; ++j) { sums4[n][j] = 0.f; sqs4[n][j] = 0.f; }
#pragma unroll
  for (int m = 0; m < 4; ++m) {
    int row = brow + wr * 64 + m * 16 + l15;
    bool ok = row < M;
    long rb = (long)(ok ? row : 0) * NOUT;
    long tb = (addtab && ok) ? (long)ele[row] * NOUT : 0;
#pragma unroll
    for (int n = 0; n < 4; ++n) {
      int col0 = bcol + wc * 64 + n * 16 + kg * 4;
      f32x4 v = acc[m][n];
      if (addtab && ok) {
        float4 tv = *reinterpret_cast<const float4*>(&tab[tb + col0]);
        v[0] += tv.x; v[1] += tv.y; v[2] += tv.z; v[3] += tv.w;
      }
      if (ok) {
        if (wf32) {
          *reinterpret_cast<f32x4*>(&outf[rb + col0]) = v;
        } else {
          u16x4 pk;
          pk.x = f2b(v[0]); pk.y = f2b(v[1]); pk.z = f2b(v[2]); pk.w = f2b(v[3]);
          *reinterpret_cast<u16x4*>(&outp[rb + col0]) = pk;
        }
#pragma unroll
        for (int j = 0; j < 4; ++j) { sums4[n][j] += v[j]; sqs4[n][j] += v[j] * v[j]; }
      }
    }
  }
  if (dostats) {
#pragma unroll
    for (int n = 0; n < 4; ++n)
#pragma unroll
      for (int d = 1; d < 16; d <<= 1)
#pragma unroll
        for (int j = 0; j < 4; ++j) {
          sums4[n][j] += __shfl_xor(sums4[n][j], d);
          sqs4[n][j] += __shfl_xor(sqs4[n][j], d);
        }
    if (l15 == 0) {
#pragma unroll
      for (int n = 0; n < 4; ++n) {
        int col0 = bcol + wc * 64 + n * 16 + kg * 4;
#pragma unroll
        for (int j = 0; j < 4; ++j) {
          atomicAdd(&csum[col0 + j], sums4[n][j]);
          atomicAdd(&csq[col0 + j], sqs4[n][j]);
        }
      }
    }
  }
}

// ---------------- host ----------------
extern "C" void kernel_launch(void* const* d_in, const int* in_sizes, int n_in,
                              void* d_out, int out_size, void* d_ws, size_t ws_size,
                              hipStream_t stream) {
  const float* x    = (const float*)d_in[0];
  const float* dist = (const float*)d_in[1];
  const int* ele    = (const int*)d_in[3];
  const float* l1w  = (const float*)d_in[4];
  const float* l1g  = (const float*)d_in[6];
  const float* l1be = (const float*)d_in[7];
  const float* l2w  = (const float*)d_in[8];
  const float* l2g  = (const float*)d_in[10];
  const float* l2be = (const float*)d_in[11];
  const float* fw   = (const float*)d_in[12];
  const float* fg   = (const float*)d_in[14];
  const float* fbe  = (const float*)d_in[15];

  int N = in_sizes[0] / 1024;  // 100000
  float* out = (float*)d_out;
  u16* xbf = (u16*)d_out;      // bf16 x overlays d_out (exact size, dead by final write)

  int MT = (N + 127) / 128;    // 782

  char* w = (char*)d_ws;
  auto alloc = [&](size_t bytes) {
    char* p = w;
    w += (bytes + 255) & ~(size_t)255;
    return p;
  };
  u16* dist_bf = (u16*)alloc((size_t)N * 256 * 2);
  u16* hp      = (u16*)alloc((size_t)N * NOUT * 2);
  u16* h       = (u16*)alloc((size_t)N * NOUT * 2);
  u16* mean    = (u16*)alloc((size_t)NSEG * NOUT * 2);
  u16* w1bt    = (u16*)alloc((size_t)NOUT * 1280 * 2);
  u16* w2bt    = (u16*)alloc((size_t)NOUT * 1280 * 2);
  u16* fbt     = (u16*)alloc((size_t)NOUT * 1024 * 2);
  float* mc2   = (float*)alloc((size_t)NSEG * NOUT * 4);
  float* mc3   = (float*)alloc((size_t)NSEG * NOUT * 4);
  float* colsum = (float*)alloc(NOUT * 4 * 2);
  float* colsumsq = colsum + NOUT;
  float* bnA   = (float*)alloc(NOUT * 4);
  float* bnC   = (float*)alloc(NOUT * 4);
  int* seg_cnt = (int*)alloc(NSEG * 4);
  int* seg_off = (int*)alloc(NSEG * 4);
  int* seg_fill = (int*)alloc(NSEG * 4);
  int* rows    = (int*)alloc((size_t)N * 4);

  size_t need = (size_t)(w - (char*)d_ws);
  if (need > ws_size) {
    fprintf(stderr, "kernel_launch: ws too small: need %zu have %zu\n", need, ws_size);
    return;
  }

  long n4x = (long)N * 1024 / 4;
  long n4d = (long)N * 256 / 4;
  long n4h = (long)N * NOUT / 4;
  int gemmGrid = MT * 4;          // 3128
  int mcGrid = (NSEG / 128) * 4;  // 32

  // casts
  k_cast<<<4096, 256, 0, stream>>>(x, xbf, n4x);
  k_cast<<<2048, 256, 0, stream>>>(dist, dist_bf, n4d);
  dim3 wt1(1280 / 32, 16), wt3(1024 / 32, 16);
  k_wtcastT<<<wt1, 256, 0, stream>>>(l1w, w1bt, 1280);
  k_wtcastT<<<wt1, 256, 0, stream>>>(l2w, w2bt, 1280);
  k_wtcastT<<<wt3, 256, 0, stream>>>(fw, fbt, 1024);

  // segment sort
  hipMemsetAsync(seg_cnt, 0, NSEG * 4, stream);
  hipMemsetAsync(seg_fill, 0, NSEG * 4, stream);
  k_hist<<<512, 256, 0, stream>>>(ele, seg_cnt, N);
  k_scan<<<1, NSEG, 0, stream>>>(seg_cnt, seg_off);
  k_scatter<<<512, 256, 0, stream>>>(ele, seg_off, seg_fill, rows, N);

  // ---- layer 1: A = [x(1024) | dist(256)], K=1280 ----
  hipMemsetAsync(colsum, 0, NOUT * 4 * 2, stream);
  k_gemm<<<gemmGrid, 256, 0, stream>>>(xbf, dist_bf, 1024, 1024, 256, 0, 0, ele,
                                       w1bt, 1280, 1280, 0, mc2, 0,
                                       hp, mc2, 0, colsum, colsumsq, 1, N, 1280);
  k_finalize<<<1, NOUT, 0, stream>>>(colsum, colsumsq, l1g, l1be, bnA, bnC, N);
  k_bnseg<<<NSEG, 256, 0, stream>>>(hp, h, mean, bnA, bnC, seg_off, seg_cnt, rows);

  // ---- layer 2: mc2 = mean @ W2[512:1024); A = [h(512) | dist(256)], K=768 ----
  k_gemm<<<mcGrid, 256, 0, stream>>>(mean, mean, 512, 512, 512, 0, 0, ele,
                                     w2bt + 512, 1280, 512, 0, mc2, 0,
                                     hp, mc2, 1, colsum, colsumsq, 0, NSEG, 512);
  k_gemm<<<gemmGrid, 256, 0, stream>>>(h, dist_bf, 512, 512, 256, 0, 0, ele,
                                       w2bt, 1280, 512, 512, mc2, 1,
                                       hp, mc2, 0, colsum, colsumsq, 1, N, 768);
  k_finalize<<<1, NOUT, 0, stream>>>(colsum, colsumsq, l2g, l2be, bnA, bnC, N);
  k_bnseg<<<NSEG, 256, 0, stream>>>(hp, h, mean, bnA, bnC, seg_off, seg_cnt, rows);

  // ---- final layer: mc3 = mean @ F[512:1024); A = h, K=512 ----
  k_gemm<<<mcGrid, 256, 0, stream>>>(mean, mean, 512, 512, 512, 0, 0, ele,
                                     fbt + 512, 1024, 512, 0, mc3, 0,
                                     hp, mc3, 1, colsum, colsumsq, 0, NSEG, 512);
  k_gemm<<<gemmGrid, 256, 0, stream>>>(h, h, 512, 512, 512, 0, 0, ele,
                                       fbt, 1024, 512, 0, mc3, 1,
                                       hp, mc3, 0, colsum, colsumsq, 1, N, 512);
  k_finalize<<<1, NOUT, 0, stream>>>(colsum, colsumsq, fg, fbe, bnA, bnC, N);
  k_final<<<4096, 256, 0, stream>>>(hp, out, bnA, bnC, n4h);
}

// Round 12
// 950.948 us; speedup vs baseline: 3.6590x; 2.8227x over previous
//
#include <hip/hip_runtime.h>
#include <stdint.h>
#include <stdio.h>

#define NOUT 512
#define NSEG 1024

typedef unsigned short u16;
typedef __attribute__((ext_vector_type(4))) float f32x4;
typedef __attribute__((ext_vector_type(8))) short s16x8;
typedef __attribute__((ext_vector_type(4))) unsigned short u16x4;

__device__ __forceinline__ u16 f2b(float f) {
  union { float f; uint32_t u; } v; v.f = f;
  uint32_t r = v.u + 0x7FFFu + ((v.u >> 16) & 1u);
  return (u16)(r >> 16);
}
__device__ __forceinline__ float b2f(u16 b) {
  union { uint32_t u; float f; } v; v.u = ((uint32_t)b) << 16;
  return v.f;
}

typedef __attribute__((address_space(1))) const void GAS;
typedef __attribute__((address_space(3))) void LAS;
__device__ __forceinline__ void llds16(const void* g, void* l) {
  __builtin_amdgcn_global_load_lds((GAS*)g, (LAS*)l, 16, 0, 0);
}

// ---------------- fused input casts (x and dist in one launch) ----------------
__global__ void k_cast2(const float* __restrict__ x, u16* __restrict__ xb, long n4x,
                        const float* __restrict__ d, u16* __restrict__ db, long n4d) {
  long i0 = blockIdx.x * (long)blockDim.x + threadIdx.x;
  long stride = (long)gridDim.x * blockDim.x;
  for (long i = i0; i < n4x; i += stride) {
    float4 v = reinterpret_cast<const float4*>(x)[i];
    u16x4 o;
    o.x = f2b(v.x); o.y = f2b(v.y); o.z = f2b(v.z); o.w = f2b(v.w);
    reinterpret_cast<u16x4*>(xb)[i] = o;
  }
  for (long i = i0; i < n4d; i += stride) {
    float4 v = reinterpret_cast<const float4*>(d)[i];
    u16x4 o;
    o.x = f2b(v.x); o.y = f2b(v.y); o.z = f2b(v.z); o.w = f2b(v.w);
    reinterpret_cast<u16x4*>(db)[i] = o;
  }
}

// w: [K][512] f32 -> out: [512][K] bf16 (B^T), coalesced both sides via LDS tile
__global__ void k_wtcastT(const float* __restrict__ w, u16* __restrict__ out, int K) {
  __shared__ float tile[32][33];
  int k0 = blockIdx.x * 32, c0 = blockIdx.y * 32;
  int t = threadIdx.x;  // 256
  int rr = t >> 5, cc = t & 31;
#pragma unroll
  for (int p = 0; p < 4; ++p)
    tile[p * 8 + rr][cc] = w[(long)(k0 + p * 8 + rr) * NOUT + c0 + cc];
  __syncthreads();
#pragma unroll
  for (int p = 0; p < 4; ++p)
    out[(long)(c0 + p * 8 + rr) * K + k0 + cc] = f2b(tile[cc][p * 8 + rr]);
}

// ---------------- segment sort ----------------
__global__ void k_hist(const int* __restrict__ ele, int* __restrict__ cnt, int N) {
  int i = blockIdx.x * blockDim.x + threadIdx.x;
  int stride = gridDim.x * blockDim.x;
  for (; i < N; i += stride) atomicAdd(&cnt[ele[i]], 1);
}

__global__ void k_scan(const int* __restrict__ cnt, int* __restrict__ off) {
  __shared__ int tmp[NSEG];
  int t = threadIdx.x;
  tmp[t] = cnt[t];
  __syncthreads();
  for (int o = 1; o < NSEG; o <<= 1) {
    int add = (t >= o) ? tmp[t - o] : 0;
    __syncthreads();
    tmp[t] += add;
    __syncthreads();
  }
  off[t] = tmp[t] - cnt[t];
}

__global__ void k_scatter(const int* __restrict__ ele, const int* __restrict__ off,
                          int* __restrict__ fill, int* __restrict__ rows, int N) {
  int i = blockIdx.x * blockDim.x + threadIdx.x;
  int stride = gridDim.x * blockDim.x;
  for (; i < N; i += stride) {
    int e = ele[i];
    int p = atomicAdd(&fill[e], 1);
    rows[off[e] + p] = i;
  }
}

// ---------------- BN finalize (self-clears accumulators for the next layer) ----------------
__global__ void k_finalize(float* __restrict__ sum, float* __restrict__ sumsq,
                           const float* __restrict__ g, const float* __restrict__ be,
                           float* __restrict__ A, float* __restrict__ C, int M) {
  int c = threadIdx.x;  // 512
  float m = sum[c] / (float)M;
  float v = sumsq[c] / (float)M - m * m;
  float a = g[c] * rsqrtf(v + 1e-5f);
  A[c] = a;
  C[c] = be[c] - a * m;
  sum[c] = 0.f;
  sumsq[c] = 0.f;
}

// ---------------- fused BN-apply + ReLU + segment mean (full row per block) ----------------
__global__ void k_bnseg(const u16* __restrict__ hp, u16* __restrict__ h, u16* __restrict__ mean,
                        const float* __restrict__ A, const float* __restrict__ C,
                        const int* __restrict__ off, const int* __restrict__ cnt,
                        const int* __restrict__ rows) {
  int s = blockIdx.x;
  int c0 = 2 * threadIdx.x;  // 256 threads -> cols c0, c0+1
  int n = cnt[s], o = off[s];
  float a0 = A[c0], a1 = A[c0 + 1], cc0 = C[c0], cc1 = C[c0 + 1];
  float s0 = 0.f, s1 = 0.f;
#pragma unroll 2
  for (int j = 0; j < n; ++j) {
    int r = rows[o + j];
    uint32_t v = *reinterpret_cast<const uint32_t*>(&hp[(long)r * NOUT + c0]);
    float h0 = fmaxf(a0 * b2f((u16)(v & 0xffff)) + cc0, 0.f);
    float h1 = fmaxf(a1 * b2f((u16)(v >> 16)) + cc1, 0.f);
    s0 += h0; s1 += h1;
    *reinterpret_cast<uint32_t*>(&h[(long)r * NOUT + c0]) =
        ((uint32_t)f2b(h1) << 16) | (uint32_t)f2b(h0);
  }
  float inv = 1.f / fmaxf((float)n, 1.f);
  *reinterpret_cast<uint32_t*>(&mean[(long)s * NOUT + c0]) =
      ((uint32_t)f2b(s1 * inv) << 16) | (uint32_t)f2b(s0 * inv);
}

__global__ void k_final(const u16* __restrict__ hp, float* __restrict__ out,
                        const float* __restrict__ A, const float* __restrict__ C, long n4) {
  long i = blockIdx.x * (long)blockDim.x + threadIdx.x;
  long stride = (long)gridDim.x * blockDim.x;
  for (; i < n4; i += stride) {
    u16x4 v = reinterpret_cast<const u16x4*>(hp)[i];
    int c0 = (int)((i * 4) & (NOUT - 1));
    float4 a = *reinterpret_cast<const float4*>(&A[c0]);
    float4 c = *reinterpret_cast<const float4*>(&C[c0]);
    float4 o;
    o.x = fmaxf(a.x * b2f(v.x) + c.x, 0.f);
    o.y = fmaxf(a.y * b2f(v.y) + c.y, 0.f);
    o.z = fmaxf(a.z * b2f(v.z) + c.z, 0.f);
    o.w = fmaxf(a.w * b2f(v.w) + c.w, 0.f);
    reinterpret_cast<float4*>(out)[i] = o;
  }
}

// ---------------- GEMM: C[M,512] = A[M,K] @ W[K,512] ----------------
// R9-verbatim (known-good codegen: VGPR 56, acc in AGPRs, zero spill).
// 2-PHASE pipelined: dual 16KB LDS buffers; per K-tile:
//   STAGE(buf^1, t+1) -> ds_read(buf cur) -> MFMA -> __syncthreads (vmcnt(0) drain
//   lands AFTER compute, so next-tile loads fly under the MFMAs).
// Tile 128x128, BK=32, 4 waves 2x2 (64x64 each), launch_bounds(256,4).
// LDS [128][32] u16; conflict-free swizzle: 16B-chunk ^= (row>>1)&3 (measured 0
// conflicts), inverse-permuted GLOBAL source (m173) + XOR on ds_read (rule #21).
// NOTE: epilogue must read acc SCALAR-wise; f32x4 copies of acc (R10/R11) demote
// the accumulator to scratch (2.3GB spill traffic, 3x slowdown).
// A: 2 regions (k<e0 -> p0 gather?g0 else p1 gather?g1). B: wbt [512][ldb] (=W^T),
// k += bskip when k>=e0b. Biases dropped (cancel in training-mode BN).
__global__ __launch_bounds__(256, 4) void k_gemm(
    const u16* p0, const u16* p1, int e0, int w0, int w1, int g0, int g1,
    const int* __restrict__ ele,
    const u16* __restrict__ wbt, int ldb, int e0b, int bskip,
    const float* __restrict__ tab, int addtab,
    u16* __restrict__ outp, float* __restrict__ outf, int wf32,
    float* __restrict__ csum, float* __restrict__ csq, int dostats,
    int M, int K) {
  __shared__ __align__(16) u16 As[2 * 4096];
  __shared__ __align__(16) u16 Bs[2 * 4096];

  int nwg = gridDim.x;
  int orig = blockIdx.x;
  // bijective XCD swizzle (m204)
  int q = nwg >> 3, r8 = nwg & 7;
  int xcd = orig & 7, loc = orig >> 3;
  int bid = (xcd < r8 ? xcd * (q + 1) : r8 * (q + 1) + (xcd - r8) * q) + loc;
  int mt = bid >> 2, ct = bid & 3;  // 4 col-tiles of same mt adjacent -> L2 A reuse
  int brow = mt * 128, bcol = ct * 128;

  int tid = (int)threadIdx.x;
  int lane = tid & 63;
  int wid = tid >> 6;
  int wr = wid >> 1, wc = wid & 1;  // 2x2 waves, 64x64 each
  int l15 = lane & 15, kg = lane >> 4;

  // staging: thread t -> row srow(+64), chunk tid&3; source chunk inverse-swizzled
  int srow = tid >> 2;                             // 0..63
  int soct = ((tid & 3) ^ ((srow >> 1) & 3)) * 8;  // u16 source col-octet

  int gr0 = brow + srow, gr1 = gr0 + 64;
  int gr0c = gr0 < M ? gr0 : M - 1;
  int gr1c = gr1 < M ? gr1 : M - 1;
  int el0 = ele[gr0c], el1 = ele[gr1c];

  const u16* a00 = p0 + (long)(g0 ? el0 : gr0c) * w0 + soct;
  const u16* a01 = p1 + (long)(g1 ? el0 : gr0c) * w1 + soct - e0;
  const u16* a10 = p0 + (long)(g0 ? el1 : gr1c) * w0 + soct;
  const u16* a11 = p1 + (long)(g1 ? el1 : gr1c) * w1 + soct - e0;

  const u16* b0p = wbt + (long)(bcol + srow) * ldb + soct;        // cols < 512
  const u16* b1p = wbt + (long)(bcol + srow + 64) * ldb + soct;

  // swizzled fragment-read offsets (u16 index within one 4096-u16 buffer)
  int xoct = (kg ^ ((l15 >> 1) & 3)) * 8;
  int aro = (wr * 64 + l15) * 32 + xoct;
  int bro = (wc * 64 + l15) * 32 + xoct;

  f32x4 acc[4][4];
#pragma unroll
  for (int m = 0; m < 4; ++m)
#pragma unroll
    for (int n = 0; n < 4; ++n)
#pragma unroll
      for (int j = 0; j < 4; ++j) acc[m][n][j] = 0.f;

  int KT = K >> 5;
  int dst = wid * 512;  // u16: per-wave linear 1KB dest region

  auto stage = [&](int tt, int buf) {
    int k0 = tt << 5;
    const u16* sa0 = k0 < e0 ? a00 : a01;
    const u16* sa1 = k0 < e0 ? a10 : a11;
    int bo = k0 + (k0 >= e0b ? bskip : 0);
    int ab = buf * 4096 + dst;
    llds16(sa0 + k0, &As[ab]);
    llds16(sa1 + k0, &As[ab + 2048]);
    llds16(b0p + bo, &Bs[ab]);
    llds16(b1p + bo, &Bs[ab + 2048]);
  };

  stage(0, 0);
  __syncthreads();

  for (int t = 0; t < KT; ++t) {
    int cur = t & 1;
    if (t + 1 < KT) stage(t + 1, cur ^ 1);
    __builtin_amdgcn_sched_barrier(0);
    const u16* Ab = &As[cur * 4096];
    const u16* Bb = &Bs[cur * 4096];
    s16x8 af[4], bf[4];
#pragma unroll
    for (int m = 0; m < 4; ++m)
      af[m] = *reinterpret_cast<const s16x8*>(&Ab[m * 512 + aro]);
#pragma unroll
    for (int n = 0; n < 4; ++n)
      bf[n] = *reinterpret_cast<const s16x8*>(&Bb[n * 512 + bro]);
#pragma unroll
    for (int m = 0; m < 4; ++m)
#pragma unroll
      for (int n = 0; n < 4; ++n)
        acc[m][n] = __builtin_amdgcn_mfma_f32_16x16x32_bf16(af[m], bf[n], acc[m][n], 0, 0, 0);
    __syncthreads();  // drain after MFMA: next-tile loads had the full phase to land
  }

  // epilogue: C layout col = lane&15, row = kg*4+j (m89-verified); scalar acc reads only
  float sums[4] = {0.f, 0.f, 0.f, 0.f}, sqs[4] = {0.f, 0.f, 0.f, 0.f};
#pragma unroll
  for (int m = 0; m < 4; ++m) {
    int row0 = brow + wr * 64 + m * 16 + kg * 4;
#pragma unroll
    for (int j = 0; j < 4; ++j) {
      int r = row0 + j;
      if (r < M) {
        long rb = (long)r * NOUT;
        long tb = addtab ? (long)ele[r] * NOUT : 0;
#pragma unroll
        for (int n = 0; n < 4; ++n) {
          int col = bcol + wc * 64 + n * 16 + l15;
          float v = acc[m][n][j];
          if (addtab) v += tab[tb + col];
          if (wf32) outf[rb + col] = v;
          else outp[rb + col] = f2b(v);
          sums[n] += v;
          sqs[n] += v * v;
        }
      }
    }
  }
  if (dostats) {
#pragma unroll
    for (int n = 0; n < 4; ++n) {
      sums[n] += __shfl_xor(sums[n], 16);
      sums[n] += __shfl_xor(sums[n], 32);
      sqs[n] += __shfl_xor(sqs[n], 16);
      sqs[n] += __shfl_xor(sqs[n], 32);
    }
    if (kg == 0) {
#pragma unroll
      for (int n = 0; n < 4; ++n) {
        int col = bcol + wc * 64 + n * 16 + l15;
        atomicAdd(&csum[col], sums[n]);
        atomicAdd(&csq[col], sqs[n]);
      }
    }
  }
}

// ---------------- host ----------------
extern "C" void kernel_launch(void* const* d_in, const int* in_sizes, int n_in,
                              void* d_out, int out_size, void* d_ws, size_t ws_size,
                              hipStream_t stream) {
  const float* x    = (const float*)d_in[0];
  const float* dist = (const float*)d_in[1];
  const int* ele    = (const int*)d_in[3];
  const float* l1w  = (const float*)d_in[4];
  const float* l1g  = (const float*)d_in[6];
  const float* l1be = (const float*)d_in[7];
  const float* l2w  = (const float*)d_in[8];
  const float* l2g  = (const float*)d_in[10];
  const float* l2be = (const float*)d_in[11];
  const float* fw   = (const float*)d_in[12];
  const float* fg   = (const float*)d_in[14];
  const float* fbe  = (const float*)d_in[15];

  int N = in_sizes[0] / 1024;  // 100000
  float* out = (float*)d_out;
  u16* xbf = (u16*)d_out;      // bf16 x overlays d_out (exact size, dead by final write)

  int MT = (N + 127) / 128;    // 782

  char* w = (char*)d_ws;
  auto alloc = [&](size_t bytes) {
    char* p = w;
    w += (bytes + 255) & ~(size_t)255;
    return p;
  };
  u16* dist_bf = (u16*)alloc((size_t)N * 256 * 2);
  u16* hp      = (u16*)alloc((size_t)N * NOUT * 2);
  u16* h       = (u16*)alloc((size_t)N * NOUT * 2);
  u16* mean    = (u16*)alloc((size_t)NSEG * NOUT * 2);
  u16* w1bt    = (u16*)alloc((size_t)NOUT * 1280 * 2);
  u16* w2bt    = (u16*)alloc((size_t)NOUT * 1280 * 2);
  u16* fbt     = (u16*)alloc((size_t)NOUT * 1024 * 2);
  float* mc2   = (float*)alloc((size_t)NSEG * NOUT * 4);
  float* mc3   = (float*)alloc((size_t)NSEG * NOUT * 4);
  float* colsum = (float*)alloc(NOUT * 4 * 2);
  float* colsumsq = colsum + NOUT;
  float* bnA   = (float*)alloc(NOUT * 4);
  float* bnC   = (float*)alloc(NOUT * 4);
  int* seg_cnt = (int*)alloc(NSEG * 4);
  int* seg_off = (int*)alloc(NSEG * 4);
  int* seg_fill = (int*)alloc(NSEG * 4);
  int* rows    = (int*)alloc((size_t)N * 4);

  size_t need = (size_t)(w - (char*)d_ws);
  if (need > ws_size) {
    fprintf(stderr, "kernel_launch: ws too small: need %zu have %zu\n", need, ws_size);
    return;
  }

  long n4x = (long)N * 1024 / 4;
  long n4d = (long)N * 256 / 4;
  long n4h = (long)N * NOUT / 4;
  int gemmGrid = MT * 4;          // 3128
  int mcGrid = (NSEG / 128) * 4;  // 32

  // fused input casts
  k_cast2<<<4096, 256, 0, stream>>>(x, xbf, n4x, dist, dist_bf, n4d);
  dim3 wt1(1280 / 32, 16), wt3(1024 / 32, 16);
  k_wtcastT<<<wt1, 256, 0, stream>>>(l1w, w1bt, 1280);
  k_wtcastT<<<wt1, 256, 0, stream>>>(l2w, w2bt, 1280);
  k_wtcastT<<<wt3, 256, 0, stream>>>(fw, fbt, 1024);

  // segment sort
  hipMemsetAsync(seg_cnt, 0, NSEG * 4, stream);
  hipMemsetAsync(seg_fill, 0, NSEG * 4, stream);
  hipMemsetAsync(colsum, 0, NOUT * 4 * 2, stream);
  k_hist<<<512, 256, 0, stream>>>(ele, seg_cnt, N);
  k_scan<<<1, NSEG, 0, stream>>>(seg_cnt, seg_off);
  k_scatter<<<512, 256, 0, stream>>>(ele, seg_off, seg_fill, rows, N);

  // ---- layer 1: A = [x(1024) | dist(256)], K=1280 ----
  k_gemm<<<gemmGrid, 256, 0, stream>>>(xbf, dist_bf, 1024, 1024, 256, 0, 0, ele,
                                       w1bt, 1280, 1280, 0, mc2, 0,
                                       hp, mc2, 0, colsum, colsumsq, 1, N, 1280);
  k_finalize<<<1, NOUT, 0, stream>>>(colsum, colsumsq, l1g, l1be, bnA, bnC, N);
  k_bnseg<<<NSEG, 256, 0, stream>>>(hp, h, mean, bnA, bnC, seg_off, seg_cnt, rows);

  // ---- layer 2: mc2 = mean @ W2[512:1024); A = [h(512) | dist(256)], K=768 ----
  k_gemm<<<mcGrid, 256, 0, stream>>>(mean, mean, 512, 512, 512, 0, 0, ele,
                                     w2bt + 512, 1280, 512, 0, mc2, 0,
                                     hp, mc2, 1, colsum, colsumsq, 0, NSEG, 512);
  k_gemm<<<gemmGrid, 256, 0, stream>>>(h, dist_bf, 512, 512, 256, 0, 0, ele,
                                       w2bt, 1280, 512, 512, mc2, 1,
                                       hp, mc2, 0, colsum, colsumsq, 1, N, 768);
  k_finalize<<<1, NOUT, 0, stream>>>(colsum, colsumsq, l2g, l2be, bnA, bnC, N);
  k_bnseg<<<NSEG, 256, 0, stream>>>(hp, h, mean, bnA, bnC, seg_off, seg_cnt, rows);

  // ---- final layer: mc3 = mean @ F[512:1024); A = h, K=512 ----
  k_gemm<<<mcGrid, 256, 0, stream>>>(mean, mean, 512, 512, 512, 0, 0, ele,
                                     fbt + 512, 1024, 512, 0, mc3, 0,
                                     hp, mc3, 1, colsum, colsumsq, 0, NSEG, 512);
  k_gemm<<<gemmGrid, 256, 0, stream>>>(h, h, 512, 512, 512, 0, 0, ele,
                                       fbt, 1024, 512, 0, mc3, 1,
                                       hp, mc3, 0, colsum, colsumsq, 1, N, 512);
  k_finalize<<<1, NOUT, 0, stream>>>(colsum, colsumsq, fg, fbe, bnA, bnC, N);
  k_final<<<4096, 256, 0, stream>>>(hp, out, bnA, bnC, n4h);
}

// Round 13
// 932.129 us; speedup vs baseline: 3.7329x; 1.0202x over previous
//
#include <hip/hip_runtime.h>
#include <stdint.h>
#include <stdio.h>

#define NOUT 512
#define NSEG 1024

typedef unsigned short u16;
typedef __attribute__((ext_vector_type(4))) float f32x4;
typedef __attribute__((ext_vector_type(8))) short s16x8;
typedef __attribute__((ext_vector_type(4))) unsigned short u16x4;

__device__ __forceinline__ u16 f2b(float f) {
  union { float f; uint32_t u; } v; v.f = f;
  uint32_t r = v.u + 0x7FFFu + ((v.u >> 16) & 1u);
  return (u16)(r >> 16);
}
__device__ __forceinline__ float b2f(u16 b) {
  union { uint32_t u; float f; } v; v.u = ((uint32_t)b) << 16;
  return v.f;
}

typedef __attribute__((address_space(1))) const void GAS;
typedef __attribute__((address_space(3))) void LAS;
__device__ __forceinline__ void llds16(const void* g, void* l) {
  __builtin_amdgcn_global_load_lds((GAS*)g, (LAS*)l, 16, 0, 0);
}

// ---------------- fused input casts (x and dist in one launch) ----------------
__global__ void k_cast2(const float* __restrict__ x, u16* __restrict__ xb, long n4x,
                        const float* __restrict__ d, u16* __restrict__ db, long n4d) {
  long i0 = blockIdx.x * (long)blockDim.x + threadIdx.x;
  long stride = (long)gridDim.x * blockDim.x;
  for (long i = i0; i < n4x; i += stride) {
    float4 v = reinterpret_cast<const float4*>(x)[i];
    u16x4 o;
    o.x = f2b(v.x); o.y = f2b(v.y); o.z = f2b(v.z); o.w = f2b(v.w);
    reinterpret_cast<u16x4*>(xb)[i] = o;
  }
  for (long i = i0; i < n4d; i += stride) {
    float4 v = reinterpret_cast<const float4*>(d)[i];
    u16x4 o;
    o.x = f2b(v.x); o.y = f2b(v.y); o.z = f2b(v.z); o.w = f2b(v.w);
    reinterpret_cast<u16x4*>(db)[i] = o;
  }
}

// All three weight transposes in one launch: z selects {l1w,l2w,fw}.
// w: [K][512] f32 -> out: [512][K] bf16 (B^T), coalesced both sides via LDS tile.
__global__ void k_wtcastT3(const float* __restrict__ w0, u16* __restrict__ o0,
                           const float* __restrict__ w1, u16* __restrict__ o1,
                           const float* __restrict__ w2, u16* __restrict__ o2) {
  __shared__ float tile[32][33];
  int z = blockIdx.z;
  const float* w = z == 0 ? w0 : (z == 1 ? w1 : w2);
  u16* out = z == 0 ? o0 : (z == 1 ? o1 : o2);
  int K = z == 2 ? 1024 : 1280;
  int k0 = blockIdx.x * 32, c0 = blockIdx.y * 32;
  if (k0 >= K) return;
  int t = threadIdx.x;  // 256
  int rr = t >> 5, cc = t & 31;
#pragma unroll
  for (int p = 0; p < 4; ++p)
    tile[p * 8 + rr][cc] = w[(long)(k0 + p * 8 + rr) * NOUT + c0 + cc];
  __syncthreads();
#pragma unroll
  for (int p = 0; p < 4; ++p)
    out[(long)(c0 + p * 8 + rr) * K + k0 + cc] = f2b(tile[cc][p * 8 + rr]);
}

// ---------------- segment sort ----------------
__global__ void k_hist(const int* __restrict__ ele, int* __restrict__ cnt, int N) {
  int i = blockIdx.x * blockDim.x + threadIdx.x;
  int stride = gridDim.x * blockDim.x;
  for (; i < N; i += stride) atomicAdd(&cnt[ele[i]], 1);
}

__global__ void k_scan(const int* __restrict__ cnt, int* __restrict__ off) {
  __shared__ int tmp[NSEG];
  int t = threadIdx.x;
  tmp[t] = cnt[t];
  __syncthreads();
  for (int o = 1; o < NSEG; o <<= 1) {
    int add = (t >= o) ? tmp[t - o] : 0;
    __syncthreads();
    tmp[t] += add;
    __syncthreads();
  }
  off[t] = tmp[t] - cnt[t];
}

__global__ void k_scatter(const int* __restrict__ ele, const int* __restrict__ off,
                          int* __restrict__ fill, int* __restrict__ rows, int N) {
  int i = blockIdx.x * blockDim.x + threadIdx.x;
  int stride = gridDim.x * blockDim.x;
  for (; i < N; i += stride) {
    int e = ele[i];
    int p = atomicAdd(&fill[e], 1);
    rows[off[e] + p] = i;
  }
}

// ---------------- fused BN-finalize + apply + ReLU + segment mean ----------------
// stats = [sum(512) | sumsq(512)]; finalize folded in (2 cols/thread, trivial VALU).
__global__ void k_bnseg(const u16* __restrict__ hp, u16* __restrict__ h, u16* __restrict__ mean,
                        const float* __restrict__ stats, const float* __restrict__ g,
                        const float* __restrict__ be, float invM,
                        const int* __restrict__ off, const int* __restrict__ cnt,
                        const int* __restrict__ rows) {
  int s = blockIdx.x;
  int c0 = 2 * threadIdx.x;  // 256 threads -> cols c0, c0+1
  int n = cnt[s], o = off[s];
  float m0 = stats[c0] * invM, m1 = stats[c0 + 1] * invM;
  float v0 = stats[NOUT + c0] * invM - m0 * m0;
  float v1 = stats[NOUT + c0 + 1] * invM - m1 * m1;
  float a0 = g[c0] * rsqrtf(v0 + 1e-5f);
  float a1 = g[c0 + 1] * rsqrtf(v1 + 1e-5f);
  float cc0 = be[c0] - a0 * m0;
  float cc1 = be[c0 + 1] - a1 * m1;
  float s0 = 0.f, s1 = 0.f;
#pragma unroll 2
  for (int j = 0; j < n; ++j) {
    int r = rows[o + j];
    uint32_t v = *reinterpret_cast<const uint32_t*>(&hp[(long)r * NOUT + c0]);
    float h0 = fmaxf(a0 * b2f((u16)(v & 0xffff)) + cc0, 0.f);
    float h1 = fmaxf(a1 * b2f((u16)(v >> 16)) + cc1, 0.f);
    s0 += h0; s1 += h1;
    *reinterpret_cast<uint32_t*>(&h[(long)r * NOUT + c0]) =
        ((uint32_t)f2b(h1) << 16) | (uint32_t)f2b(h0);
  }
  float inv = 1.f / fmaxf((float)n, 1.f);
  *reinterpret_cast<uint32_t*>(&mean[(long)s * NOUT + c0]) =
      ((uint32_t)f2b(s1 * inv) << 16) | (uint32_t)f2b(s0 * inv);
}

// ---------------- final BN+ReLU to f32 out; finalize computed once per block into LDS ----------------
__global__ void k_final(const u16* __restrict__ hp, float* __restrict__ out,
                        const float* __restrict__ stats, const float* __restrict__ g,
                        const float* __restrict__ be, float invM, long n4) {
  __shared__ float sA[NOUT], sC[NOUT];
  for (int c = threadIdx.x; c < NOUT; c += blockDim.x) {
    float m = stats[c] * invM;
    float v = stats[NOUT + c] * invM - m * m;
    float a = g[c] * rsqrtf(v + 1e-5f);
    sA[c] = a;
    sC[c] = be[c] - a * m;
  }
  __syncthreads();
  long i = blockIdx.x * (long)blockDim.x + threadIdx.x;
  long stride = (long)gridDim.x * blockDim.x;
  for (; i < n4; i += stride) {
    u16x4 v = reinterpret_cast<const u16x4*>(hp)[i];
    int c0 = (int)((i * 4) & (NOUT - 1));
    float4 a = *reinterpret_cast<const float4*>(&sA[c0]);
    float4 c = *reinterpret_cast<const float4*>(&sC[c0]);
    float4 o;
    o.x = fmaxf(a.x * b2f(v.x) + c.x, 0.f);
    o.y = fmaxf(a.y * b2f(v.y) + c.y, 0.f);
    o.z = fmaxf(a.z * b2f(v.z) + c.z, 0.f);
    o.w = fmaxf(a.w * b2f(v.w) + c.w, 0.f);
    reinterpret_cast<float4*>(out)[i] = o;
  }
}

// ---------------- GEMM: C[M,512] = A[M,K] @ W[K,512] ----------------
// R12-verbatim (known-good codegen: VGPR 56, acc in AGPRs, zero spill).
// 2-PHASE pipelined: dual 16KB LDS buffers; per K-tile:
//   STAGE(buf^1, t+1) -> ds_read(buf cur) -> MFMA -> __syncthreads (vmcnt(0) drain
//   lands AFTER compute, so next-tile loads fly under the MFMAs).
// Tile 128x128, BK=32, 4 waves 2x2 (64x64 each), launch_bounds(256,4).
// LDS [128][32] u16; conflict-free swizzle: 16B-chunk ^= (row>>1)&3 (measured 0
// conflicts), inverse-permuted GLOBAL source (m173) + XOR on ds_read (rule #21).
// NOTE: epilogue must read acc SCALAR-wise; f32x4 copies of acc (R10/R11) demote
// the accumulator to scratch (2.3GB spill traffic, 3x slowdown).
// A: 2 regions (k<e0 -> p0 gather?g0 else p1 gather?g1). B: wbt [512][ldb] (=W^T),
// k += bskip when k>=e0b. Biases dropped (cancel in training-mode BN).
__global__ __launch_bounds__(256, 4) void k_gemm(
    const u16* p0, const u16* p1, int e0, int w0, int w1, int g0, int g1,
    const int* __restrict__ ele,
    const u16* __restrict__ wbt, int ldb, int e0b, int bskip,
    const float* __restrict__ tab, int addtab,
    u16* __restrict__ outp, float* __restrict__ outf, int wf32,
    float* __restrict__ csum, float* __restrict__ csq, int dostats,
    int M, int K) {
  __shared__ __align__(16) u16 As[2 * 4096];
  __shared__ __align__(16) u16 Bs[2 * 4096];

  int nwg = gridDim.x;
  int orig = blockIdx.x;
  // bijective XCD swizzle (m204)
  int q = nwg >> 3, r8 = nwg & 7;
  int xcd = orig & 7, loc = orig >> 3;
  int bid = (xcd < r8 ? xcd * (q + 1) : r8 * (q + 1) + (xcd - r8) * q) + loc;
  int mt = bid >> 2, ct = bid & 3;  // 4 col-tiles of same mt adjacent -> L2 A reuse
  int brow = mt * 128, bcol = ct * 128;

  int tid = (int)threadIdx.x;
  int lane = tid & 63;
  int wid = tid >> 6;
  int wr = wid >> 1, wc = wid & 1;  // 2x2 waves, 64x64 each
  int l15 = lane & 15, kg = lane >> 4;

  // staging: thread t -> row srow(+64), chunk tid&3; source chunk inverse-swizzled
  int srow = tid >> 2;                             // 0..63
  int soct = ((tid & 3) ^ ((srow >> 1) & 3)) * 8;  // u16 source col-octet

  int gr0 = brow + srow, gr1 = gr0 + 64;
  int gr0c = gr0 < M ? gr0 : M - 1;
  int gr1c = gr1 < M ? gr1 : M - 1;
  int el0 = ele[gr0c], el1 = ele[gr1c];

  const u16* a00 = p0 + (long)(g0 ? el0 : gr0c) * w0 + soct;
  const u16* a01 = p1 + (long)(g1 ? el0 : gr0c) * w1 + soct - e0;
  const u16* a10 = p0 + (long)(g0 ? el1 : gr1c) * w0 + soct;
  const u16* a11 = p1 + (long)(g1 ? el1 : gr1c) * w1 + soct - e0;

  const u16* b0p = wbt + (long)(bcol + srow) * ldb + soct;        // cols < 512
  const u16* b1p = wbt + (long)(bcol + srow + 64) * ldb + soct;

  // swizzled fragment-read offsets (u16 index within one 4096-u16 buffer)
  int xoct = (kg ^ ((l15 >> 1) & 3)) * 8;
  int aro = (wr * 64 + l15) * 32 + xoct;
  int bro = (wc * 64 + l15) * 32 + xoct;

  f32x4 acc[4][4];
#pragma unroll
  for (int m = 0; m < 4; ++m)
#pragma unroll
    for (int n = 0; n < 4; ++n)
#pragma unroll
      for (int j = 0; j < 4; ++j) acc[m][n][j] = 0.f;

  int KT = K >> 5;
  int dst = wid * 512;  // u16: per-wave linear 1KB dest region

  auto stage = [&](int tt, int buf) {
    int k0 = tt << 5;
    const u16* sa0 = k0 < e0 ? a00 : a01;
    const u16* sa1 = k0 < e0 ? a10 : a11;
    int bo = k0 + (k0 >= e0b ? bskip : 0);
    int ab = buf * 4096 + dst;
    llds16(sa0 + k0, &As[ab]);
    llds16(sa1 + k0, &As[ab + 2048]);
    llds16(b0p + bo, &Bs[ab]);
    llds16(b1p + bo, &Bs[ab + 2048]);
  };

  stage(0, 0);
  __syncthreads();

  for (int t = 0; t < KT; ++t) {
    int cur = t & 1;
    if (t + 1 < KT) stage(t + 1, cur ^ 1);
    __builtin_amdgcn_sched_barrier(0);
    const u16* Ab = &As[cur * 4096];
    const u16* Bb = &Bs[cur * 4096];
    s16x8 af[4], bf[4];
#pragma unroll
    for (int m = 0; m < 4; ++m)
      af[m] = *reinterpret_cast<const s16x8*>(&Ab[m * 512 + aro]);
#pragma unroll
    for (int n = 0; n < 4; ++n)
      bf[n] = *reinterpret_cast<const s16x8*>(&Bb[n * 512 + bro]);
#pragma unroll
    for (int m = 0; m < 4; ++m)
#pragma unroll
      for (int n = 0; n < 4; ++n)
        acc[m][n] = __builtin_amdgcn_mfma_f32_16x16x32_bf16(af[m], bf[n], acc[m][n], 0, 0, 0);
    __syncthreads();  // drain after MFMA: next-tile loads had the full phase to land
  }

  // epilogue: C layout col = lane&15, row = kg*4+j (m89-verified); scalar acc reads only
  float sums[4] = {0.f, 0.f, 0.f, 0.f}, sqs[4] = {0.f, 0.f, 0.f, 0.f};
#pragma unroll
  for (int m = 0; m < 4; ++m) {
    int row0 = brow + wr * 64 + m * 16 + kg * 4;
#pragma unroll
    for (int j = 0; j < 4; ++j) {
      int r = row0 + j;
      if (r < M) {
        long rb = (long)r * NOUT;
        long tb = addtab ? (long)ele[r] * NOUT : 0;
#pragma unroll
        for (int n = 0; n < 4; ++n) {
          int col = bcol + wc * 64 + n * 16 + l15;
          float v = acc[m][n][j];
          if (addtab) v += tab[tb + col];
          if (wf32) outf[rb + col] = v;
          else outp[rb + col] = f2b(v);
          sums[n] += v;
          sqs[n] += v * v;
        }
      }
    }
  }
  if (dostats) {
#pragma unroll
    for (int n = 0; n < 4; ++n) {
      sums[n] += __shfl_xor(sums[n], 16);
      sums[n] += __shfl_xor(sums[n], 32);
      sqs[n] += __shfl_xor(sqs[n], 16);
      sqs[n] += __shfl_xor(sqs[n], 32);
    }
    if (kg == 0) {
#pragma unroll
      for (int n = 0; n < 4; ++n) {
        int col = bcol + wc * 64 + n * 16 + l15;
        atomicAdd(&csum[col], sums[n]);
        atomicAdd(&csq[col], sqs[n]);
      }
    }
  }
}

// ---------------- host ----------------
extern "C" void kernel_launch(void* const* d_in, const int* in_sizes, int n_in,
                              void* d_out, int out_size, void* d_ws, size_t ws_size,
                              hipStream_t stream) {
  const float* x    = (const float*)d_in[0];
  const float* dist = (const float*)d_in[1];
  const int* ele    = (const int*)d_in[3];
  const float* l1w  = (const float*)d_in[4];
  const float* l1g  = (const float*)d_in[6];
  const float* l1be = (const float*)d_in[7];
  const float* l2w  = (const float*)d_in[8];
  const float* l2g  = (const float*)d_in[10];
  const float* l2be = (const float*)d_in[11];
  const float* fw   = (const float*)d_in[12];
  const float* fg   = (const float*)d_in[14];
  const float* fbe  = (const float*)d_in[15];

  int N = in_sizes[0] / 1024;  // 100000
  float* out = (float*)d_out;
  u16* xbf = (u16*)d_out;      // bf16 x overlays d_out (exact size, dead by final write)

  int MT = (N + 127) / 128;    // 782

  char* w = (char*)d_ws;
  auto alloc = [&](size_t bytes) {
    char* p = w;
    w += (bytes + 255) & ~(size_t)255;
    return p;
  };
  u16* dist_bf = (u16*)alloc((size_t)N * 256 * 2);
  u16* hp      = (u16*)alloc((size_t)N * NOUT * 2);
  u16* h       = (u16*)alloc((size_t)N * NOUT * 2);
  u16* mean    = (u16*)alloc((size_t)NSEG * NOUT * 2);
  u16* w1bt    = (u16*)alloc((size_t)NOUT * 1280 * 2);
  u16* w2bt    = (u16*)alloc((size_t)NOUT * 1280 * 2);
  u16* fbt     = (u16*)alloc((size_t)NOUT * 1024 * 2);
  float* mc2   = (float*)alloc((size_t)NSEG * NOUT * 4);
  float* mc3   = (float*)alloc((size_t)NSEG * NOUT * 4);
  // ---- contiguous zero-zone: seg_cnt, seg_fill, stats1..3 (single memset) ----
  char* zz0    = w;
  int* seg_cnt = (int*)alloc(NSEG * 4);
  int* seg_fill = (int*)alloc(NSEG * 4);
  float* stats1 = (float*)alloc(NOUT * 2 * 4);  // [sum(512) | sumsq(512)]
  float* stats2 = (float*)alloc(NOUT * 2 * 4);
  float* stats3 = (float*)alloc(NOUT * 2 * 4);
  size_t zzlen = (size_t)(w - zz0);
  int* seg_off = (int*)alloc(NSEG * 4);
  int* rows    = (int*)alloc((size_t)N * 4);

  size_t need = (size_t)(w - (char*)d_ws);
  if (need > ws_size) {
    fprintf(stderr, "kernel_launch: ws too small: need %zu have %zu\n", need, ws_size);
    return;
  }

  long n4x = (long)N * 1024 / 4;
  long n4d = (long)N * 256 / 4;
  long n4h = (long)N * NOUT / 4;
  int gemmGrid = MT * 4;          // 3128
  int mcGrid = (NSEG / 128) * 4;  // 32
  float invM = 1.0f / (float)N;

  // input casts + weight transposes (2 launches) + one zero-zone memset
  k_cast2<<<4096, 256, 0, stream>>>(x, xbf, n4x, dist, dist_bf, n4d);
  dim3 wtg(1280 / 32, NOUT / 32, 3);
  k_wtcastT3<<<wtg, 256, 0, stream>>>(l1w, w1bt, l2w, w2bt, fw, fbt);
  hipMemsetAsync(zz0, 0, zzlen, stream);

  // segment sort
  k_hist<<<512, 256, 0, stream>>>(ele, seg_cnt, N);
  k_scan<<<1, NSEG, 0, stream>>>(seg_cnt, seg_off);
  k_scatter<<<512, 256, 0, stream>>>(ele, seg_off, seg_fill, rows, N);

  // ---- layer 1: A = [x(1024) | dist(256)], K=1280 ----
  k_gemm<<<gemmGrid, 256, 0, stream>>>(xbf, dist_bf, 1024, 1024, 256, 0, 0, ele,
                                       w1bt, 1280, 1280, 0, mc2, 0,
                                       hp, mc2, 0, stats1, stats1 + NOUT, 1, N, 1280);
  k_bnseg<<<NSEG, 256, 0, stream>>>(hp, h, mean, stats1, l1g, l1be, invM,
                                    seg_off, seg_cnt, rows);

  // ---- layer 2: mc2 = mean @ W2[512:1024); A = [h(512) | dist(256)], K=768 ----
  k_gemm<<<mcGrid, 256, 0, stream>>>(mean, mean, 512, 512, 512, 0, 0, ele,
                                     w2bt + 512, 1280, 512, 0, mc2, 0,
                                     hp, mc2, 1, stats2, stats2 + NOUT, 0, NSEG, 512);
  k_gemm<<<gemmGrid, 256, 0, stream>>>(h, dist_bf, 512, 512, 256, 0, 0, ele,
                                       w2bt, 1280, 512, 512, mc2, 1,
                                       hp, mc2, 0, stats2, stats2 + NOUT, 1, N, 768);
  k_bnseg<<<NSEG, 256, 0, stream>>>(hp, h, mean, stats2, l2g, l2be, invM,
                                    seg_off, seg_cnt, rows);

  // ---- final layer: mc3 = mean @ F[512:1024); A = h, K=512 ----
  k_gemm<<<mcGrid, 256, 0, stream>>>(mean, mean, 512, 512, 512, 0, 0, ele,
                                     fbt + 512, 1024, 512, 0, mc3, 0,
                                     hp, mc3, 1, stats3, stats3 + NOUT, 0, NSEG, 512);
  k_gemm<<<gemmGrid, 256, 0, stream>>>(h, h, 512, 512, 512, 0, 0, ele,
                                       fbt, 1024, 512, 0, mc3, 1,
                                       hp, mc3, 0, stats3, stats3 + NOUT, 1, N, 512);
  k_final<<<4096, 256, 0, stream>>>(hp, out, stats3, fg, fbe, invM, n4h);
}

// Round 14
// 932.036 us; speedup vs baseline: 3.7333x; 1.0001x over previous
//
#include <hip/hip_runtime.h>
#include <stdint.h>
#include <stdio.h>

#define NOUT 512
#define NSEG 1024

typedef unsigned short u16;
typedef __attribute__((ext_vector_type(4))) float f32x4;
typedef __attribute__((ext_vector_type(8))) short s16x8;
typedef __attribute__((ext_vector_type(4))) unsigned short u16x4;

__device__ __forceinline__ u16 f2b(float f) {
  union { float f; uint32_t u; } v; v.f = f;
  uint32_t r = v.u + 0x7FFFu + ((v.u >> 16) & 1u);
  return (u16)(r >> 16);
}
__device__ __forceinline__ float b2f(u16 b) {
  union { uint32_t u; float f; } v; v.u = ((uint32_t)b) << 16;
  return v.f;
}

typedef __attribute__((address_space(1))) const void GAS;
typedef __attribute__((address_space(3))) void LAS;
__device__ __forceinline__ void llds16(const void* g, void* l) {
  __builtin_amdgcn_global_load_lds((GAS*)g, (LAS*)l, 16, 0, 0);
}

// ---------------- dist cast (x cast is fused into the L1 GEMM) ----------------
__global__ void k_castd(const float* __restrict__ d, u16* __restrict__ db, long n4d) {
  long i = blockIdx.x * (long)blockDim.x + threadIdx.x;
  long stride = (long)gridDim.x * blockDim.x;
  for (; i < n4d; i += stride) {
    float4 v = reinterpret_cast<const float4*>(d)[i];
    u16x4 o;
    o.x = f2b(v.x); o.y = f2b(v.y); o.z = f2b(v.z); o.w = f2b(v.w);
    reinterpret_cast<u16x4*>(db)[i] = o;
  }
}

// All three weight transposes in one launch: z selects {l1w,l2w,fw}.
// w: [K][512] f32 -> out: [512][K] bf16 (B^T), coalesced both sides via LDS tile.
__global__ void k_wtcastT3(const float* __restrict__ w0, u16* __restrict__ o0,
                           const float* __restrict__ w1, u16* __restrict__ o1,
                           const float* __restrict__ w2, u16* __restrict__ o2) {
  __shared__ float tile[32][33];
  int z = blockIdx.z;
  const float* w = z == 0 ? w0 : (z == 1 ? w1 : w2);
  u16* out = z == 0 ? o0 : (z == 1 ? o1 : o2);
  int K = z == 2 ? 1024 : 1280;
  int k0 = blockIdx.x * 32, c0 = blockIdx.y * 32;
  if (k0 >= K) return;
  int t = threadIdx.x;  // 256
  int rr = t >> 5, cc = t & 31;
#pragma unroll
  for (int p = 0; p < 4; ++p)
    tile[p * 8 + rr][cc] = w[(long)(k0 + p * 8 + rr) * NOUT + c0 + cc];
  __syncthreads();
#pragma unroll
  for (int p = 0; p < 4; ++p)
    out[(long)(c0 + p * 8 + rr) * K + k0 + cc] = f2b(tile[cc][p * 8 + rr]);
}

// ---------------- segment sort ----------------
__global__ void k_hist(const int* __restrict__ ele, int* __restrict__ cnt, int N) {
  int i = blockIdx.x * blockDim.x + threadIdx.x;
  int stride = gridDim.x * blockDim.x;
  for (; i < N; i += stride) atomicAdd(&cnt[ele[i]], 1);
}

__global__ void k_scan(const int* __restrict__ cnt, int* __restrict__ off) {
  __shared__ int tmp[NSEG];
  int t = threadIdx.x;
  tmp[t] = cnt[t];
  __syncthreads();
  for (int o = 1; o < NSEG; o <<= 1) {
    int add = (t >= o) ? tmp[t - o] : 0;
    __syncthreads();
    tmp[t] += add;
    __syncthreads();
  }
  off[t] = tmp[t] - cnt[t];
}

__global__ void k_scatter(const int* __restrict__ ele, const int* __restrict__ off,
                          int* __restrict__ fill, int* __restrict__ rows, int N) {
  int i = blockIdx.x * blockDim.x + threadIdx.x;
  int stride = gridDim.x * blockDim.x;
  for (; i < N; i += stride) {
    int e = ele[i];
    int p = atomicAdd(&fill[e], 1);
    rows[off[e] + p] = i;
  }
}

// ---------------- fused BN-finalize + apply + ReLU + segment mean ----------------
__global__ void k_bnseg(const u16* __restrict__ hp, u16* __restrict__ h, u16* __restrict__ mean,
                        const float* __restrict__ stats, const float* __restrict__ g,
                        const float* __restrict__ be, float invM,
                        const int* __restrict__ off, const int* __restrict__ cnt,
                        const int* __restrict__ rows) {
  int s = blockIdx.x;
  int c0 = 2 * threadIdx.x;  // 256 threads -> cols c0, c0+1
  int n = cnt[s], o = off[s];
  float m0 = stats[c0] * invM, m1 = stats[c0 + 1] * invM;
  float v0 = stats[NOUT + c0] * invM - m0 * m0;
  float v1 = stats[NOUT + c0 + 1] * invM - m1 * m1;
  float a0 = g[c0] * rsqrtf(v0 + 1e-5f);
  float a1 = g[c0 + 1] * rsqrtf(v1 + 1e-5f);
  float cc0 = be[c0] - a0 * m0;
  float cc1 = be[c0 + 1] - a1 * m1;
  float s0 = 0.f, s1 = 0.f;
#pragma unroll 2
  for (int j = 0; j < n; ++j) {
    int r = rows[o + j];
    uint32_t v = *reinterpret_cast<const uint32_t*>(&hp[(long)r * NOUT + c0]);
    float h0 = fmaxf(a0 * b2f((u16)(v & 0xffff)) + cc0, 0.f);
    float h1 = fmaxf(a1 * b2f((u16)(v >> 16)) + cc1, 0.f);
    s0 += h0; s1 += h1;
    *reinterpret_cast<uint32_t*>(&h[(long)r * NOUT + c0]) =
        ((uint32_t)f2b(h1) << 16) | (uint32_t)f2b(h0);
  }
  float inv = 1.f / fmaxf((float)n, 1.f);
  *reinterpret_cast<uint32_t*>(&mean[(long)s * NOUT + c0]) =
      ((uint32_t)f2b(s1 * inv) << 16) | (uint32_t)f2b(s0 * inv);
}

// ---------------- final BN+ReLU to f32 out; finalize once per block into LDS ----------------
__global__ void k_final(const u16* __restrict__ hp, float* __restrict__ out,
                        const float* __restrict__ stats, const float* __restrict__ g,
                        const float* __restrict__ be, float invM, long n4) {
  __shared__ float sA[NOUT], sC[NOUT];
  for (int c = threadIdx.x; c < NOUT; c += blockDim.x) {
    float m = stats[c] * invM;
    float v = stats[NOUT + c] * invM - m * m;
    float a = g[c] * rsqrtf(v + 1e-5f);
    sA[c] = a;
    sC[c] = be[c] - a * m;
  }
  __syncthreads();
  long i = blockIdx.x * (long)blockDim.x + threadIdx.x;
  long stride = (long)gridDim.x * blockDim.x;
  for (; i < n4; i += stride) {
    u16x4 v = reinterpret_cast<const u16x4*>(hp)[i];
    int c0 = (int)((i * 4) & (NOUT - 1));
    float4 a = *reinterpret_cast<const float4*>(&sA[c0]);
    float4 c = *reinterpret_cast<const float4*>(&sC[c0]);
    float4 o;
    o.x = fmaxf(a.x * b2f(v.x) + c.x, 0.f);
    o.y = fmaxf(a.y * b2f(v.y) + c.y, 0.f);
    o.z = fmaxf(a.z * b2f(v.z) + c.z, 0.f);
    o.w = fmaxf(a.w * b2f(v.w) + c.w, 0.f);
    reinterpret_cast<float4*>(out)[i] = o;
  }
}

// ---------------- GEMM: C[M,512] = A[M,K] @ W[K,512] ----------------
// R13-verbatim 2-phase loop. FA=0: bf16 A staged via gload_lds (VGPR 56, zero spill).
// FA=1 (layer 1): A sourced as f32 (x | dist) staged DIRECTLY into a f32 LDS tile via
// gload_lds (no registers live across MFMA -> no R10-style spill), converted to bf16
// between ds_read and MFMA with f2b (numerics identical to the standalone cast).
// f32 tile [128][32]f32: 16B-unit u at row r holds global unit u^(r&7); write side is
// linear per wave-call (chunk wid*4+i, lane*16B) with the inverse permutation folded
// into the per-thread global source (rule #21); frag read units (2kg)^(l15&7), ^1 ->
// even 8-way unit spread (2-way/bank = free). LDS 48KB -> 3 blocks/CU.
// NOTE: epilogue reads acc SCALAR-wise only (f32x4 copies of acc demote it to scratch).
template <int FA>
__global__ __launch_bounds__(256, FA ? 3 : 4) void k_gemm(
    const u16* p0, const u16* p1, const float* fx, const float* fd,
    int e0, int w0, int w1, int g0, int g1,
    const int* __restrict__ ele,
    const u16* __restrict__ wbt, int ldb, int e0b, int bskip,
    const float* __restrict__ tab, int addtab,
    u16* __restrict__ outp, float* __restrict__ outf, int wf32,
    float* __restrict__ csum, float* __restrict__ csq, int dostats,
    int M, int K) {
  __shared__ __align__(16) u16 AsU[FA ? 2 * 8192 : 2 * 4096];
  __shared__ __align__(16) u16 Bs[2 * 4096];
  float* AsF = reinterpret_cast<float*>(AsU);

  int nwg = gridDim.x;
  int orig = blockIdx.x;
  // bijective XCD swizzle (m204)
  int q = nwg >> 3, r8 = nwg & 7;
  int xcd = orig & 7, loc = orig >> 3;
  int bid = (xcd < r8 ? xcd * (q + 1) : r8 * (q + 1) + (xcd - r8) * q) + loc;
  int mt = bid >> 2, ct = bid & 3;  // 4 col-tiles of same mt adjacent -> L2 A reuse
  int brow = mt * 128, bcol = ct * 128;

  int tid = (int)threadIdx.x;
  int lane = tid & 63;
  int wid = tid >> 6;
  int wr = wid >> 1, wc = wid & 1;  // 2x2 waves, 64x64 each
  int l15 = lane & 15, kg = lane >> 4;

  // staging (bf16 path): thread t -> row srow(+64), chunk tid&3; source inverse-swizzled
  int srow = tid >> 2;                             // 0..63
  int soct = ((tid & 3) ^ ((srow >> 1) & 3)) * 8;  // u16 source col-octet

  const u16 *a00 = nullptr, *a01 = nullptr, *a10 = nullptr, *a11 = nullptr;
  const float *fxa[4], *fda[4];
  if constexpr (FA) {
    int swz4 = ((lane & 7) ^ ((lane >> 3) & 7)) * 4;  // f32 source col offset
#pragma unroll
    for (int i = 0; i < 4; ++i) {
      int c = wid * 4 + i;
      int gr = brow + c * 8 + (lane >> 3);
      if (gr >= M) gr = M - 1;
      fxa[i] = fx + (long)gr * w0 + swz4;
      fda[i] = fd + (long)gr * w1 + swz4;
    }
  } else {
    int gr0 = brow + srow, gr1 = gr0 + 64;
    int gr0c = gr0 < M ? gr0 : M - 1;
    int gr1c = gr1 < M ? gr1 : M - 1;
    int el0 = (g0 | g1) ? ele[gr0c] : 0, el1 = (g0 | g1) ? ele[gr1c] : 0;
    a00 = p0 + (long)(g0 ? el0 : gr0c) * w0 + soct;
    a01 = p1 + (long)(g1 ? el0 : gr0c) * w1 + soct - e0;
    a10 = p0 + (long)(g0 ? el1 : gr1c) * w0 + soct;
    a11 = p1 + (long)(g1 ? el1 : gr1c) * w1 + soct - e0;
  }

  const u16* b0p = wbt + (long)(bcol + srow) * ldb + soct;        // cols < 512
  const u16* b1p = wbt + (long)(bcol + srow + 64) * ldb + soct;

  // swizzled fragment-read offsets (u16 index within one 4096-u16 buffer)
  int xoct = (kg ^ ((l15 >> 1) & 3)) * 8;
  int aro = (wr * 64 + l15) * 32 + xoct;
  int bro = (wc * 64 + l15) * 32 + xoct;

  f32x4 acc[4][4];
#pragma unroll
  for (int m = 0; m < 4; ++m)
#pragma unroll
    for (int n = 0; n < 4; ++n)
#pragma unroll
      for (int j = 0; j < 4; ++j) acc[m][n][j] = 0.f;

  int KT = K >> 5;
  int dst = wid * 512;  // u16: per-wave linear 1KB dest region (B / bf16-A)

  auto stage = [&](int tt, int buf) {
    int k0 = tt << 5;
    if constexpr (FA) {
      if (k0 < e0) {
#pragma unroll
        for (int i = 0; i < 4; ++i)
          llds16(fxa[i] + k0, &AsF[buf * 4096 + (wid * 4 + i) * 256]);
      } else {
#pragma unroll
        for (int i = 0; i < 4; ++i)
          llds16(fda[i] + (k0 - e0), &AsF[buf * 4096 + (wid * 4 + i) * 256]);
      }
    } else {
      const u16* sa0 = k0 < e0 ? a00 : a01;
      const u16* sa1 = k0 < e0 ? a10 : a11;
      int ab = buf * 4096 + dst;
      llds16(sa0 + k0, &AsU[ab]);
      llds16(sa1 + k0, &AsU[ab + 2048]);
    }
    int bo = k0 + (k0 >= e0b ? bskip : 0);
    int bb = buf * 4096 + dst;
    llds16(b0p + bo, &Bs[bb]);
    llds16(b1p + bo, &Bs[bb + 2048]);
  };

  stage(0, 0);
  __syncthreads();

  for (int t = 0; t < KT; ++t) {
    int cur = t & 1;
    if (t + 1 < KT) stage(t + 1, cur ^ 1);
    __builtin_amdgcn_sched_barrier(0);
    const u16* Bb = &Bs[cur * 4096];
    s16x8 af[4], bf[4];
    if constexpr (FA) {
      int rbase = cur * 4096;
      int u1 = (2 * kg) ^ (l15 & 7);
#pragma unroll
      for (int m = 0; m < 4; ++m) {
        int ro = rbase + (wr * 64 + m * 16 + l15) * 32;
        f32x4 lo = *reinterpret_cast<const f32x4*>(&AsF[ro + u1 * 4]);
        f32x4 hi = *reinterpret_cast<const f32x4*>(&AsF[ro + (u1 ^ 1) * 4]);
        s16x8 a;
        a[0] = (short)f2b(lo[0]); a[1] = (short)f2b(lo[1]);
        a[2] = (short)f2b(lo[2]); a[3] = (short)f2b(lo[3]);
        a[4] = (short)f2b(hi[0]); a[5] = (short)f2b(hi[1]);
        a[6] = (short)f2b(hi[2]); a[7] = (short)f2b(hi[3]);
        af[m] = a;
      }
    } else {
      const u16* Ab = &AsU[cur * 4096];
#pragma unroll
      for (int m = 0; m < 4; ++m)
        af[m] = *reinterpret_cast<const s16x8*>(&Ab[m * 512 + aro]);
    }
#pragma unroll
    for (int n = 0; n < 4; ++n)
      bf[n] = *reinterpret_cast<const s16x8*>(&Bb[n * 512 + bro]);
#pragma unroll
    for (int m = 0; m < 4; ++m)
#pragma unroll
      for (int n = 0; n < 4; ++n)
        acc[m][n] = __builtin_amdgcn_mfma_f32_16x16x32_bf16(af[m], bf[n], acc[m][n], 0, 0, 0);
    __syncthreads();  // drain after MFMA: next-tile loads had the full phase to land
  }

  // epilogue: C layout col = lane&15, row = kg*4+j (m89-verified); scalar acc reads only
  float sums[4] = {0.f, 0.f, 0.f, 0.f}, sqs[4] = {0.f, 0.f, 0.f, 0.f};
#pragma unroll
  for (int m = 0; m < 4; ++m) {
    int row0 = brow + wr * 64 + m * 16 + kg * 4;
#pragma unroll
    for (int j = 0; j < 4; ++j) {
      int r = row0 + j;
      if (r < M) {
        long rb = (long)r * NOUT;
        long tb = addtab ? (long)ele[r] * NOUT : 0;
#pragma unroll
        for (int n = 0; n < 4; ++n) {
          int col = bcol + wc * 64 + n * 16 + l15;
          float v = acc[m][n][j];
          if (addtab) v += tab[tb + col];
          if (wf32) outf[rb + col] = v;
          else outp[rb + col] = f2b(v);
          sums[n] += v;
          sqs[n] += v * v;
        }
      }
    }
  }
  if (dostats) {
#pragma unroll
    for (int n = 0; n < 4; ++n) {
      sums[n] += __shfl_xor(sums[n], 16);
      sums[n] += __shfl_xor(sums[n], 32);
      sqs[n] += __shfl_xor(sqs[n], 16);
      sqs[n] += __shfl_xor(sqs[n], 32);
    }
    if (kg == 0) {
#pragma unroll
      for (int n = 0; n < 4; ++n) {
        int col = bcol + wc * 64 + n * 16 + l15;
        atomicAdd(&csum[col], sums[n]);
        atomicAdd(&csq[col], sqs[n]);
      }
    }
  }
}

// ---------------- host ----------------
extern "C" void kernel_launch(void* const* d_in, const int* in_sizes, int n_in,
                              void* d_out, int out_size, void* d_ws, size_t ws_size,
                              hipStream_t stream) {
  const float* x    = (const float*)d_in[0];
  const float* dist = (const float*)d_in[1];
  const int* ele    = (const int*)d_in[3];
  const float* l1w  = (const float*)d_in[4];
  const float* l1g  = (const float*)d_in[6];
  const float* l1be = (const float*)d_in[7];
  const float* l2w  = (const float*)d_in[8];
  const float* l2g  = (const float*)d_in[10];
  const float* l2be = (const float*)d_in[11];
  const float* fw   = (const float*)d_in[12];
  const float* fg   = (const float*)d_in[14];
  const float* fbe  = (const float*)d_in[15];

  int N = in_sizes[0] / 1024;  // 100000
  float* out = (float*)d_out;

  int MT = (N + 127) / 128;    // 782

  char* w = (char*)d_ws;
  auto alloc = [&](size_t bytes) {
    char* p = w;
    w += (bytes + 255) & ~(size_t)255;
    return p;
  };
  u16* dist_bf = (u16*)alloc((size_t)N * 256 * 2);
  u16* hp      = (u16*)alloc((size_t)N * NOUT * 2);
  u16* h       = (u16*)alloc((size_t)N * NOUT * 2);
  u16* mean    = (u16*)alloc((size_t)NSEG * NOUT * 2);
  u16* w1bt    = (u16*)alloc((size_t)NOUT * 1280 * 2);
  u16* w2bt    = (u16*)alloc((size_t)NOUT * 1280 * 2);
  u16* fbt     = (u16*)alloc((size_t)NOUT * 1024 * 2);
  float* mc2   = (float*)alloc((size_t)NSEG * NOUT * 4);
  float* mc3   = (float*)alloc((size_t)NSEG * NOUT * 4);
  // ---- contiguous zero-zone: seg_cnt, seg_fill, stats1..3 (single memset) ----
  char* zz0    = w;
  int* seg_cnt = (int*)alloc(NSEG * 4);
  int* seg_fill = (int*)alloc(NSEG * 4);
  float* stats1 = (float*)alloc(NOUT * 2 * 4);  // [sum(512) | sumsq(512)]
  float* stats2 = (float*)alloc(NOUT * 2 * 4);
  float* stats3 = (float*)alloc(NOUT * 2 * 4);
  size_t zzlen = (size_t)(w - zz0);
  int* seg_off = (int*)alloc(NSEG * 4);
  int* rows    = (int*)alloc((size_t)N * 4);

  size_t need = (size_t)(w - (char*)d_ws);
  if (need > ws_size) {
    fprintf(stderr, "kernel_launch: ws too small: need %zu have %zu\n", need, ws_size);
    return;
  }

  long n4d = (long)N * 256 / 4;
  long n4h = (long)N * NOUT / 4;
  int gemmGrid = MT * 4;          // 3128
  int mcGrid = (NSEG / 128) * 4;  // 32
  float invM = 1.0f / (float)N;

  // dist cast + weight transposes + one zero-zone memset
  k_castd<<<2048, 256, 0, stream>>>(dist, dist_bf, n4d);
  dim3 wtg(1280 / 32, NOUT / 32, 3);
  k_wtcastT3<<<wtg, 256, 0, stream>>>(l1w, w1bt, l2w, w2bt, fw, fbt);
  hipMemsetAsync(zz0, 0, zzlen, stream);

  // segment sort
  k_hist<<<512, 256, 0, stream>>>(ele, seg_cnt, N);
  k_scan<<<1, NSEG, 0, stream>>>(seg_cnt, seg_off);
  k_scatter<<<512, 256, 0, stream>>>(ele, seg_off, seg_fill, rows, N);

  // ---- layer 1: A = [x(1024,f32) | dist(256,f32)], K=1280, x-cast fused ----
  k_gemm<1><<<gemmGrid, 256, 0, stream>>>(nullptr, nullptr, x, dist,
                                          1024, 1024, 256, 0, 0, ele,
                                          w1bt, 1280, 1280, 0, mc2, 0,
                                          hp, mc2, 0, stats1, stats1 + NOUT, 1, N, 1280);
  k_bnseg<<<NSEG, 256, 0, stream>>>(hp, h, mean, stats1, l1g, l1be, invM,
                                    seg_off, seg_cnt, rows);

  // ---- layer 2: mc2 = mean @ W2[512:1024); A = [h(512) | dist(256)], K=768 ----
  k_gemm<0><<<mcGrid, 256, 0, stream>>>(mean, mean, nullptr, nullptr,
                                        512, 512, 512, 0, 0, ele,
                                        w2bt + 512, 1280, 512, 0, mc2, 0,
                                        hp, mc2, 1, stats2, stats2 + NOUT, 0, NSEG, 512);
  k_gemm<0><<<gemmGrid, 256, 0, stream>>>(h, dist_bf, nullptr, nullptr,
                                          512, 512, 256, 0, 0, ele,
                                          w2bt, 1280, 512, 512, mc2, 1,
                                          hp, mc2, 0, stats2, stats2 + NOUT, 1, N, 768);
  k_bnseg<<<NSEG, 256, 0, stream>>>(hp, h, mean, stats2, l2g, l2be, invM,
                                    seg_off, seg_cnt, rows);

  // ---- final layer: mc3 = mean @ F[512:1024); A = h, K=512 ----
  k_gemm<0><<<mcGrid, 256, 0, stream>>>(mean, mean, nullptr, nullptr,
                                        512, 512, 512, 0, 0, ele,
                                        fbt + 512, 1024, 512, 0, mc3, 0,
                                        hp, mc3, 1, stats3, stats3 + NOUT, 0, NSEG, 512);
  k_gemm<0><<<gemmGrid, 256, 0, stream>>>(h, h, nullptr, nullptr,
                                          512, 512, 512, 0, 0, ele,
                                          fbt, 1024, 512, 0, mc3, 1,
                                          hp, mc3, 0, stats3, stats3 + NOUT, 1, N, 512);
  k_final<<<4096, 256, 0, stream>>>(hp, out, stats3, fg, fbe, invM, n4h);
}

// Round 15
// 908.043 us; speedup vs baseline: 3.8319x; 1.0264x over previous
//
#include <hip/hip_runtime.h>
#include <stdint.h>
#include <stdio.h>

#define NOUT 512
#define NSEG 1024

typedef unsigned short u16;
typedef __attribute__((ext_vector_type(4))) float f32x4;
typedef __attribute__((ext_vector_type(8))) short s16x8;
typedef __attribute__((ext_vector_type(4))) unsigned short u16x4;

__device__ __forceinline__ u16 f2b(float f) {
  union { float f; uint32_t u; } v; v.f = f;
  uint32_t r = v.u + 0x7FFFu + ((v.u >> 16) & 1u);
  return (u16)(r >> 16);
}
__device__ __forceinline__ float b2f(u16 b) {
  union { uint32_t u; float f; } v; v.u = ((uint32_t)b) << 16;
  return v.f;
}

typedef __attribute__((address_space(1))) const void GAS;
typedef __attribute__((address_space(3))) void LAS;
__device__ __forceinline__ void llds16(const void* g, void* l) {
  __builtin_amdgcn_global_load_lds((GAS*)g, (LAS*)l, 16, 0, 0);
}

// ---------------- fused input casts (x and dist in one launch) ----------------
__global__ void k_cast2(const float* __restrict__ x, u16* __restrict__ xb, long n4x,
                        const float* __restrict__ d, u16* __restrict__ db, long n4d) {
  long i0 = blockIdx.x * (long)blockDim.x + threadIdx.x;
  long stride = (long)gridDim.x * blockDim.x;
  for (long i = i0; i < n4x; i += stride) {
    float4 v = reinterpret_cast<const float4*>(x)[i];
    u16x4 o;
    o.x = f2b(v.x); o.y = f2b(v.y); o.z = f2b(v.z); o.w = f2b(v.w);
    reinterpret_cast<u16x4*>(xb)[i] = o;
  }
  for (long i = i0; i < n4d; i += stride) {
    float4 v = reinterpret_cast<const float4*>(d)[i];
    u16x4 o;
    o.x = f2b(v.x); o.y = f2b(v.y); o.z = f2b(v.z); o.w = f2b(v.w);
    reinterpret_cast<u16x4*>(db)[i] = o;
  }
}

// All three weight transposes in one launch: z selects {l1w,l2w,fw}.
// w: [K][512] f32 -> out: [512][K] bf16 (B^T), coalesced both sides via LDS tile.
__global__ void k_wtcastT3(const float* __restrict__ w0, u16* __restrict__ o0,
                           const float* __restrict__ w1, u16* __restrict__ o1,
                           const float* __restrict__ w2, u16* __restrict__ o2) {
  __shared__ float tile[32][33];
  int z = blockIdx.z;
  const float* w = z == 0 ? w0 : (z == 1 ? w1 : w2);
  u16* out = z == 0 ? o0 : (z == 1 ? o1 : o2);
  int K = z == 2 ? 1024 : 1280;
  int k0 = blockIdx.x * 32, c0 = blockIdx.y * 32;
  if (k0 >= K) return;
  int t = threadIdx.x;  // 256
  int rr = t >> 5, cc = t & 31;
#pragma unroll
  for (int p = 0; p < 4; ++p)
    tile[p * 8 + rr][cc] = w[(long)(k0 + p * 8 + rr) * NOUT + c0 + cc];
  __syncthreads();
#pragma unroll
  for (int p = 0; p < 4; ++p)
    out[(long)(c0 + p * 8 + rr) * K + k0 + cc] = f2b(tile[cc][p * 8 + rr]);
}

// ---------------- segment sort ----------------
__global__ void k_hist(const int* __restrict__ ele, int* __restrict__ cnt, int N) {
  int i = blockIdx.x * blockDim.x + threadIdx.x;
  int stride = gridDim.x * blockDim.x;
  for (; i < N; i += stride) atomicAdd(&cnt[ele[i]], 1);
}

__global__ void k_scan(const int* __restrict__ cnt, int* __restrict__ off) {
  __shared__ int tmp[NSEG];
  int t = threadIdx.x;
  tmp[t] = cnt[t];
  __syncthreads();
  for (int o = 1; o < NSEG; o <<= 1) {
    int add = (t >= o) ? tmp[t - o] : 0;
    __syncthreads();
    tmp[t] += add;
    __syncthreads();
  }
  off[t] = tmp[t] - cnt[t];
}

__global__ void k_scatter(const int* __restrict__ ele, const int* __restrict__ off,
                          int* __restrict__ fill, int* __restrict__ rows, int N) {
  int i = blockIdx.x * blockDim.x + threadIdx.x;
  int stride = gridDim.x * blockDim.x;
  for (; i < N; i += stride) {
    int e = ele[i];
    int p = atomicAdd(&fill[e], 1);
    rows[off[e] + p] = i;
  }
}

// ---------------- fused BN-finalize + apply + ReLU + segment mean ----------------
__global__ void k_bnseg(const u16* __restrict__ hp, u16* __restrict__ h, u16* __restrict__ mean,
                        const float* __restrict__ stats, const float* __restrict__ g,
                        const float* __restrict__ be, float invM,
                        const int* __restrict__ off, const int* __restrict__ cnt,
                        const int* __restrict__ rows) {
  int s = blockIdx.x;
  int c0 = 2 * threadIdx.x;  // 256 threads -> cols c0, c0+1
  int n = cnt[s], o = off[s];
  float m0 = stats[c0] * invM, m1 = stats[c0 + 1] * invM;
  float v0 = stats[NOUT + c0] * invM - m0 * m0;
  float v1 = stats[NOUT + c0 + 1] * invM - m1 * m1;
  float a0 = g[c0] * rsqrtf(v0 + 1e-5f);
  float a1 = g[c0 + 1] * rsqrtf(v1 + 1e-5f);
  float cc0 = be[c0] - a0 * m0;
  float cc1 = be[c0 + 1] - a1 * m1;
  float s0 = 0.f, s1 = 0.f;
#pragma unroll 2
  for (int j = 0; j < n; ++j) {
    int r = rows[o + j];
    uint32_t v = *reinterpret_cast<const uint32_t*>(&hp[(long)r * NOUT + c0]);
    float h0 = fmaxf(a0 * b2f((u16)(v & 0xffff)) + cc0, 0.f);
    float h1 = fmaxf(a1 * b2f((u16)(v >> 16)) + cc1, 0.f);
    s0 += h0; s1 += h1;
    *reinterpret_cast<uint32_t*>(&h[(long)r * NOUT + c0]) =
        ((uint32_t)f2b(h1) << 16) | (uint32_t)f2b(h0);
  }
  float inv = 1.f / fmaxf((float)n, 1.f);
  *reinterpret_cast<uint32_t*>(&mean[(long)s * NOUT + c0]) =
      ((uint32_t)f2b(s1 * inv) << 16) | (uint32_t)f2b(s0 * inv);
}

// ---------------- final BN+ReLU to f32 out; finalize once per block into LDS ----------------
__global__ void k_final(const u16* __restrict__ hp, float* __restrict__ out,
                        const float* __restrict__ stats, const float* __restrict__ g,
                        const float* __restrict__ be, float invM, long n4) {
  __shared__ float sA[NOUT], sC[NOUT];
  for (int c = threadIdx.x; c < NOUT; c += blockDim.x) {
    float m = stats[c] * invM;
    float v = stats[NOUT + c] * invM - m * m;
    float a = g[c] * rsqrtf(v + 1e-5f);
    sA[c] = a;
    sC[c] = be[c] - a * m;
  }
  __syncthreads();
  long i = blockIdx.x * (long)blockDim.x + threadIdx.x;
  long stride = (long)gridDim.x * blockDim.x;
  for (; i < n4; i += stride) {
    u16x4 v = reinterpret_cast<const u16x4*>(hp)[i];
    int c0 = (int)((i * 4) & (NOUT - 1));
    float4 a = *reinterpret_cast<const float4*>(&sA[c0]);
    float4 c = *reinterpret_cast<const float4*>(&sC[c0]);
    float4 o;
    o.x = fmaxf(a.x * b2f(v.x) + c.x, 0.f);
    o.y = fmaxf(a.y * b2f(v.y) + c.y, 0.f);
    o.z = fmaxf(a.z * b2f(v.z) + c.z, 0.f);
    o.w = fmaxf(a.w * b2f(v.w) + c.w, 0.f);
    reinterpret_cast<float4*>(out)[i] = o;
  }
}

// ---------------- GEMM: C[M,512] = A[M,K] @ W[K,512] ----------------
// R13 2-phase loop with COMPILE-TIME K/E0/E0B/BSKIP: the K-loop fully unrolls,
// region selects and B-offsets fold to immediates, and the scheduler pipelines
// across adjacent tiles. Known-good codegen target: acc in AGPRs, zero spill
// (tripwire: WRITE_SIZE must stay ~106MB; spills showed as GBs in R10/R11).
// 2-PHASE: dual 16KB LDS buffers; per K-tile: STAGE(buf^1, t+1) -> ds_read(cur)
// -> MFMA -> __syncthreads (vmcnt(0) drain lands AFTER compute).
// Tile 128x128, BK=32, 4 waves 2x2 (64x64 each), launch_bounds(256,4).
// LDS [128][32] u16; conflict-free swizzle: 16B-chunk ^= (row>>1)&3 (measured 0
// conflicts), inverse-permuted GLOBAL source (m173) + XOR on ds_read (rule #21).
// NOTE: epilogue reads acc SCALAR-wise only (f32x4 copies of acc -> scratch).
// A: 2 regions (k<E0 -> p0 gather?g0 else p1 gather?g1). B: wbt [512][ldb] (=W^T),
// k += BSKIP when k>=E0B. Biases dropped (cancel in training-mode BN).
template <int K, int E0, int E0B, int BSKIP>
__global__ __launch_bounds__(256, 4) void k_gemm(
    const u16* p0, const u16* p1, int w0, int w1, int g0, int g1,
    const int* __restrict__ ele,
    const u16* __restrict__ wbt, int ldb,
    const float* __restrict__ tab, int addtab,
    u16* __restrict__ outp, float* __restrict__ outf, int wf32,
    float* __restrict__ csum, float* __restrict__ csq, int dostats,
    int M) {
  __shared__ __align__(16) u16 As[2 * 4096];
  __shared__ __align__(16) u16 Bs[2 * 4096];

  int nwg = gridDim.x;
  int orig = blockIdx.x;
  // bijective XCD swizzle (m204)
  int q = nwg >> 3, r8 = nwg & 7;
  int xcd = orig & 7, loc = orig >> 3;
  int bid = (xcd < r8 ? xcd * (q + 1) : r8 * (q + 1) + (xcd - r8) * q) + loc;
  int mt = bid >> 2, ct = bid & 3;  // 4 col-tiles of same mt adjacent -> L2 A reuse
  int brow = mt * 128, bcol = ct * 128;

  int tid = (int)threadIdx.x;
  int lane = tid & 63;
  int wid = tid >> 6;
  int wr = wid >> 1, wc = wid & 1;  // 2x2 waves, 64x64 each
  int l15 = lane & 15, kg = lane >> 4;

  // staging: thread t -> row srow(+64), chunk tid&3; source chunk inverse-swizzled
  int srow = tid >> 2;                             // 0..63
  int soct = ((tid & 3) ^ ((srow >> 1) & 3)) * 8;  // u16 source col-octet

  int gr0 = brow + srow, gr1 = gr0 + 64;
  int gr0c = gr0 < M ? gr0 : M - 1;
  int gr1c = gr1 < M ? gr1 : M - 1;
  int el0 = (g0 | g1) ? ele[gr0c] : 0, el1 = (g0 | g1) ? ele[gr1c] : 0;

  const u16* a00 = p0 + (long)(g0 ? el0 : gr0c) * w0 + soct;
  const u16* a01 = p1 + (long)(g1 ? el0 : gr0c) * w1 + soct - E0;
  const u16* a10 = p0 + (long)(g0 ? el1 : gr1c) * w0 + soct;
  const u16* a11 = p1 + (long)(g1 ? el1 : gr1c) * w1 + soct - E0;

  const u16* b0p = wbt + (long)(bcol + srow) * ldb + soct;        // cols < 512
  const u16* b1p = wbt + (long)(bcol + srow + 64) * ldb + soct;

  // swizzled fragment-read offsets (u16 index within one 4096-u16 buffer)
  int xoct = (kg ^ ((l15 >> 1) & 3)) * 8;
  int aro = (wr * 64 + l15) * 32 + xoct;
  int bro = (wc * 64 + l15) * 32 + xoct;

  f32x4 acc[4][4];
#pragma unroll
  for (int m = 0; m < 4; ++m)
#pragma unroll
    for (int n = 0; n < 4; ++n)
#pragma unroll
      for (int j = 0; j < 4; ++j) acc[m][n][j] = 0.f;

  constexpr int KT = K >> 5;
  int dst = wid * 512;  // u16: per-wave linear 1KB dest region

  auto stage = [&](int tt, int buf) {
    int k0 = tt << 5;
    const u16* sa0 = k0 < E0 ? a00 : a01;
    const u16* sa1 = k0 < E0 ? a10 : a11;
    int bo = k0 + (k0 >= E0B ? BSKIP : 0);
    int ab = buf * 4096 + dst;
    llds16(sa0 + k0, &As[ab]);
    llds16(sa1 + k0, &As[ab + 2048]);
    llds16(b0p + bo, &Bs[ab]);
    llds16(b1p + bo, &Bs[ab + 2048]);
  };

  stage(0, 0);
  __syncthreads();

#pragma unroll
  for (int t = 0; t < KT; ++t) {
    int cur = t & 1;
    if (t + 1 < KT) stage(t + 1, cur ^ 1);
    __builtin_amdgcn_sched_barrier(0);
    const u16* Ab = &As[cur * 4096];
    const u16* Bb = &Bs[cur * 4096];
    s16x8 af[4], bf[4];
#pragma unroll
    for (int m = 0; m < 4; ++m)
      af[m] = *reinterpret_cast<const s16x8*>(&Ab[m * 512 + aro]);
#pragma unroll
    for (int n = 0; n < 4; ++n)
      bf[n] = *reinterpret_cast<const s16x8*>(&Bb[n * 512 + bro]);
#pragma unroll
    for (int m = 0; m < 4; ++m)
#pragma unroll
      for (int n = 0; n < 4; ++n)
        acc[m][n] = __builtin_amdgcn_mfma_f32_16x16x32_bf16(af[m], bf[n], acc[m][n], 0, 0, 0);
    __syncthreads();  // drain after MFMA: next-tile loads had the full phase to land
  }

  // epilogue: C layout col = lane&15, row = kg*4+j (m89-verified); scalar acc reads only
  float sums[4] = {0.f, 0.f, 0.f, 0.f}, sqs[4] = {0.f, 0.f, 0.f, 0.f};
#pragma unroll
  for (int m = 0; m < 4; ++m) {
    int row0 = brow + wr * 64 + m * 16 + kg * 4;
#pragma unroll
    for (int j = 0; j < 4; ++j) {
      int r = row0 + j;
      if (r < M) {
        long rb = (long)r * NOUT;
        long tb = addtab ? (long)ele[r] * NOUT : 0;
#pragma unroll
        for (int n = 0; n < 4; ++n) {
          int col = bcol + wc * 64 + n * 16 + l15;
          float v = acc[m][n][j];
          if (addtab) v += tab[tb + col];
          if (wf32) outf[rb + col] = v;
          else outp[rb + col] = f2b(v);
          sums[n] += v;
          sqs[n] += v * v;
        }
      }
    }
  }
  if (dostats) {
#pragma unroll
    for (int n = 0; n < 4; ++n) {
      sums[n] += __shfl_xor(sums[n], 16);
      sums[n] += __shfl_xor(sums[n], 32);
      sqs[n] += __shfl_xor(sqs[n], 16);
      sqs[n] += __shfl_xor(sqs[n], 32);
    }
    if (kg == 0) {
#pragma unroll
      for (int n = 0; n < 4; ++n) {
        int col = bcol + wc * 64 + n * 16 + l15;
        atomicAdd(&csum[col], sums[n]);
        atomicAdd(&csq[col], sqs[n]);
      }
    }
  }
}

// ---------------- host ----------------
extern "C" void kernel_launch(void* const* d_in, const int* in_sizes, int n_in,
                              void* d_out, int out_size, void* d_ws, size_t ws_size,
                              hipStream_t stream) {
  const float* x    = (const float*)d_in[0];
  const float* dist = (const float*)d_in[1];
  const int* ele    = (const int*)d_in[3];
  const float* l1w  = (const float*)d_in[4];
  const float* l1g  = (const float*)d_in[6];
  const float* l1be = (const float*)d_in[7];
  const float* l2w  = (const float*)d_in[8];
  const float* l2g  = (const float*)d_in[10];
  const float* l2be = (const float*)d_in[11];
  const float* fw   = (const float*)d_in[12];
  const float* fg   = (const float*)d_in[14];
  const float* fbe  = (const float*)d_in[15];

  int N = in_sizes[0] / 1024;  // 100000
  float* out = (float*)d_out;
  u16* xbf = (u16*)d_out;      // bf16 x overlays d_out (exact size, dead by final write)

  int MT = (N + 127) / 128;    // 782

  char* w = (char*)d_ws;
  auto alloc = [&](size_t bytes) {
    char* p = w;
    w += (bytes + 255) & ~(size_t)255;
    return p;
  };
  u16* dist_bf = (u16*)alloc((size_t)N * 256 * 2);
  u16* hp      = (u16*)alloc((size_t)N * NOUT * 2);
  u16* h       = (u16*)alloc((size_t)N * NOUT * 2);
  u16* mean    = (u16*)alloc((size_t)NSEG * NOUT * 2);
  u16* w1bt    = (u16*)alloc((size_t)NOUT * 1280 * 2);
  u16* w2bt    = (u16*)alloc((size_t)NOUT * 1280 * 2);
  u16* fbt     = (u16*)alloc((size_t)NOUT * 1024 * 2);
  float* mc2   = (float*)alloc((size_t)NSEG * NOUT * 4);
  float* mc3   = (float*)alloc((size_t)NSEG * NOUT * 4);
  // ---- contiguous zero-zone: seg_cnt, seg_fill, stats1..3 (single memset) ----
  char* zz0    = w;
  int* seg_cnt = (int*)alloc(NSEG * 4);
  int* seg_fill = (int*)alloc(NSEG * 4);
  float* stats1 = (float*)alloc(NOUT * 2 * 4);  // [sum(512) | sumsq(512)]
  float* stats2 = (float*)alloc(NOUT * 2 * 4);
  float* stats3 = (float*)alloc(NOUT * 2 * 4);
  size_t zzlen = (size_t)(w - zz0);
  int* seg_off = (int*)alloc(NSEG * 4);
  int* rows    = (int*)alloc((size_t)N * 4);

  size_t need = (size_t)(w - (char*)d_ws);
  if (need > ws_size) {
    fprintf(stderr, "kernel_launch: ws too small: need %zu have %zu\n", need, ws_size);
    return;
  }

  long n4x = (long)N * 1024 / 4;
  long n4d = (long)N * 256 / 4;
  long n4h = (long)N * NOUT / 4;
  int gemmGrid = MT * 4;          // 3128
  int mcGrid = (NSEG / 128) * 4;  // 32
  float invM = 1.0f / (float)N;

  // input casts + weight transposes + one zero-zone memset
  k_cast2<<<4096, 256, 0, stream>>>(x, xbf, n4x, dist, dist_bf, n4d);
  dim3 wtg(1280 / 32, NOUT / 32, 3);
  k_wtcastT3<<<wtg, 256, 0, stream>>>(l1w, w1bt, l2w, w2bt, fw, fbt);
  hipMemsetAsync(zz0, 0, zzlen, stream);

  // segment sort
  k_hist<<<512, 256, 0, stream>>>(ele, seg_cnt, N);
  k_scan<<<1, NSEG, 0, stream>>>(seg_cnt, seg_off);
  k_scatter<<<512, 256, 0, stream>>>(ele, seg_off, seg_fill, rows, N);

  // ---- layer 1: A = [x(1024) | dist(256)], K=1280 ----
  k_gemm<1280, 1024, 1280, 0><<<gemmGrid, 256, 0, stream>>>(
      xbf, dist_bf, 1024, 256, 0, 0, ele, w1bt, 1280, mc2, 0,
      hp, mc2, 0, stats1, stats1 + NOUT, 1, N);
  k_bnseg<<<NSEG, 256, 0, stream>>>(hp, h, mean, stats1, l1g, l1be, invM,
                                    seg_off, seg_cnt, rows);

  // ---- layer 2: mc2 = mean @ W2[512:1024); A = [h(512) | dist(256)], K=768 ----
  k_gemm<512, 512, 512, 0><<<mcGrid, 256, 0, stream>>>(
      mean, mean, 512, 512, 0, 0, ele, w2bt + 512, 1280, mc2, 0,
      hp, mc2, 1, stats2, stats2 + NOUT, 0, NSEG);
  k_gemm<768, 512, 512, 512><<<gemmGrid, 256, 0, stream>>>(
      h, dist_bf, 512, 256, 0, 0, ele, w2bt, 1280, mc2, 1,
      hp, mc2, 0, stats2, stats2 + NOUT, 1, N);
  k_bnseg<<<NSEG, 256, 0, stream>>>(hp, h, mean, stats2, l2g, l2be, invM,
                                    seg_off, seg_cnt, rows);

  // ---- final layer: mc3 = mean @ F[512:1024); A = h, K=512 ----
  k_gemm<512, 512, 512, 0><<<mcGrid, 256, 0, stream>>>(
      mean, mean, 512, 512, 0, 0, ele, fbt + 512, 1024, mc3, 0,
      hp, mc3, 1, stats3, stats3 + NOUT, 0, NSEG);
  k_gemm<512, 512, 512, 0><<<gemmGrid, 256, 0, stream>>>(
      h, h, 512, 512, 0, 0, ele, fbt, 1024, mc3, 1,
      hp, mc3, 0, stats3, stats3 + NOUT, 1, N);
  k_final<<<4096, 256, 0, stream>>>(hp, out, stats3, fg, fbe, invM, n4h);
}